// Round 17
// baseline (241.401 us; speedup 1.0000x reference)
//
#include <hip/hip_runtime.h>
#include <hip/hip_bf16.h>
#include <cstdint>
#include <cstddef>

typedef unsigned short ushort_t;
typedef __bf16 bf16x8 __attribute__((ext_vector_type(8)));
typedef float f32x4 __attribute__((ext_vector_type(4)));
typedef float f32x16 __attribute__((ext_vector_type(16)));

#define D_MODEL 1024
#define D_FF 4096
#define BB 2
#define SS 2048
#define NH 16
#define MROWS (BB * SS) /* 4096 */
#define KVBLK 64

__device__ __forceinline__ ushort_t f2bf(float f) {
  union { float f; unsigned u; } x; x.f = f;
  unsigned r = x.u + 0x7fffu + ((x.u >> 16) & 1u);
  return (ushort_t)(r >> 16);
}

__device__ __forceinline__ void gload_lds16(const void* g, void* l) {
  __builtin_amdgcn_global_load_lds((const __attribute__((address_space(1))) void*)g,
                                   (__attribute__((address_space(3))) void*)l, 16, 0, 0);
}

__device__ __forceinline__ bf16x8 pack4w(unsigned w0, unsigned w1, unsigned w2, unsigned w3) {
  union { unsigned u[4]; bf16x8 v; } t;
  t.u[0] = w0; t.u[1] = w1; t.u[2] = w2; t.u[3] = w3;
  return t.v;
}

// ---------------- LayerNorm (fp32 in -> bf16 out) ----------------
__global__ __launch_bounds__(256) void ln_bf16_kernel(
    const float* __restrict__ x, const float* __restrict__ w,
    const float* __restrict__ b, ushort_t* __restrict__ out) {
  int row = blockIdx.x;
  int tid = threadIdx.x;
  int lane = tid & 63, wid = tid >> 6;
  const float4 v = ((const float4*)(x + (size_t)row * D_MODEL))[tid];
  float s = v.x + v.y + v.z + v.w;
  __shared__ float red[8];
  #pragma unroll
  for (int o = 32; o > 0; o >>= 1) s += __shfl_down(s, o);
  if (lane == 0) red[wid] = s;
  __syncthreads();
  float mu = (red[0] + red[1] + red[2] + red[3]) * (1.0f / D_MODEL);
  float d0 = v.x - mu, d1 = v.y - mu, d2 = v.z - mu, d3 = v.w - mu;
  float sq = d0 * d0 + d1 * d1 + d2 * d2 + d3 * d3;
  #pragma unroll
  for (int o = 32; o > 0; o >>= 1) sq += __shfl_down(sq, o);
  if (lane == 0) red[4 + wid] = sq;
  __syncthreads();
  float var = (red[4] + red[5] + red[6] + red[7]) * (1.0f / D_MODEL);
  float rstd = rsqrtf(var + 1e-5f);
  const float4 wv = ((const float4*)w)[tid];
  const float4 bv = ((const float4*)b)[tid];
  ushort4 o4;
  o4.x = f2bf(d0 * rstd * wv.x + bv.x);
  o4.y = f2bf(d1 * rstd * wv.y + bv.y);
  o4.z = f2bf(d2 * rstd * wv.z + bv.z);
  o4.w = f2bf(d3 * rstd * wv.w + bv.w);
  ((ushort4*)(out + (size_t)row * D_MODEL))[tid] = o4;
}

// ---------------- transpose + cast: W[K][N] fp32 -> Wt[N][K] bf16 ----------------
__global__ __launch_bounds__(256) void transpose_cast_kernel(
    const float* __restrict__ W, ushort_t* __restrict__ Wt, int K, int N) {
  __shared__ float tile[32][33];
  int bx = blockIdx.x * 32;  // n
  int by = blockIdx.y * 32;  // k
  int tx = threadIdx.x, ty = threadIdx.y;  // 32 x 8
  #pragma unroll
  for (int i = 0; i < 32; i += 8)
    tile[ty + i][tx] = W[(size_t)(by + ty + i) * N + bx + tx];
  __syncthreads();
  #pragma unroll
  for (int i = 0; i < 32; i += 8)
    Wt[(size_t)(bx + ty + i) * K + by + tx] = f2bf(tile[tx][ty + i]);
}

// 4x 1024x1024 transposes in one launch (Wq,Wk,Wv -> Wt_qkv; Wo -> Wt_o)
__global__ __launch_bounds__(256) void transpose_cast4_kernel(
    const float* __restrict__ Wq, const float* __restrict__ Wk,
    const float* __restrict__ Wv, const float* __restrict__ Wo,
    ushort_t* __restrict__ Dqkv, ushort_t* __restrict__ Do_) {
  __shared__ float tile[32][33];
  int z = blockIdx.z;
  const float* W = (z == 0) ? Wq : (z == 1) ? Wk : (z == 2) ? Wv : Wo;
  ushort_t* Wt = (z < 3) ? (Dqkv + (size_t)z * 1024 * 1024) : Do_;
  int bx = blockIdx.x * 32;
  int by = blockIdx.y * 32;
  int tx = threadIdx.x, ty = threadIdx.y;
  #pragma unroll
  for (int i = 0; i < 32; i += 8)
    tile[ty + i][tx] = W[(size_t)(by + ty + i) * 1024 + bx + tx];
  __syncthreads();
  #pragma unroll
  for (int i = 0; i < 32; i += 8)
    Wt[(size_t)(bx + ty + i) * 1024 + by + tx] = f2bf(tile[tx][ty + i]);
}

// pack bq|bk|bv -> bqkv (3072 fp32)
__global__ __launch_bounds__(256) void biaspack_kernel(
    const float* __restrict__ bq, const float* __restrict__ bk,
    const float* __restrict__ bv, float* __restrict__ out) {
  int i = blockIdx.x * 256 + threadIdx.x;
  float v = (i < 1024) ? bq[i] : (i < 2048) ? bk[i - 1024] : bv[i - 2048];
  out[i] = v;
}

// ---------------- V transpose: qkv V-slice -> Vt[bh][64 d][SS keys] bf16 ----------------
__global__ __launch_bounds__(256) void vtrans_kernel(
    const ushort_t* __restrict__ qkv, ushort_t* __restrict__ Vt) {
  __shared__ __align__(16) ushort_t T[64 * 64];  // [key][d], chunk-XOR swizzled
  const int tid = threadIdx.x;
  const int bh = blockIdx.y, b = bh >> 4, h = bh & 15;
  const int kv0 = blockIdx.x * 64;
  const ushort_t* Vp = qkv + (size_t)b * SS * 3072 + 2048 + h * 64;
  #pragma unroll
  for (int i = 0; i < 2; i++) {
    int idx = tid * 2 + i;          // chunk index
    int key = idx >> 3, c = idx & 7;
    bf16x8 v = *(const bf16x8*)(Vp + (size_t)(kv0 + key) * 3072 + c * 8);
    *(bf16x8*)(T + key * 64 + ((c ^ (key & 7)) * 8)) = v;
  }
  __syncthreads();
  int d = tid >> 2, kb = tid & 3;
  ushort_t o[16];
  #pragma unroll
  for (int j = 0; j < 16; j++) {
    int key = kb * 16 + j;
    o[j] = T[key * 64 + (((d >> 3) ^ (key & 7)) * 8) + (d & 7)];
  }
  ushort_t* dst = Vt + (size_t)(bh * 64 + d) * SS + kv0 + kb * 16;
  *(bf16x8*)dst = *(bf16x8*)&o[0];
  *(bf16x8*)(dst + 8) = *(bf16x8*)&o[8];
}

// ---------------- GEMM 128x256, BK=32, 3-buffer LDS ring (72KB -> 2 blocks/CU) ----------------
// EPI: 0 = bf16 + bias (cols<1024 scaled by Cs for QKV); 1 = bf16 + bias + relu.
template <int EPI>
__global__ __launch_bounds__(256, 2) void gemm256w_kernel(
    const ushort_t* __restrict__ A, const ushort_t* __restrict__ Bt,
    const float* __restrict__ bias, void* __restrict__ Cout,
    int M, int N, int K, int NTn) {
  __shared__ __align__(16) ushort_t ldsA[3][4096];  // 8KB each
  __shared__ __align__(16) ushort_t ldsB[3][8192];  // 16KB each
  const int tid = threadIdx.x, lane = tid & 63, wid = tid >> 6;
  const int wm = wid >> 1, wn = wid & 1;
  const int rl = lane & 15, cg = lane >> 4;
  int nwg = gridDim.x;
  int q = nwg >> 3, rr = nwg & 7;
  int xcd = blockIdx.x & 7, idx = blockIdx.x >> 3;
  int wgid = (xcd < rr ? xcd * (q + 1) : rr * (q + 1) + (xcd - rr) * q) + idx;
  const int row0 = (wgid / NTn) * 128, col0 = (wgid - (wgid / NTn) * NTn) * 256;
  const int NT = K / 32;

  int soffA[2], ldsoA[2], soffB[4], ldsoB[4];
  #pragma unroll
  for (int i = 0; i < 2; i++) {
    int ci = wid * 128 + i * 64 + lane;
    int P = ci * 16;
    int L = P ^ (((P >> 7) & 7) << 4);
    soffA[i] = (L >> 6) * K + ((L >> 4) & 3) * 8;
    ldsoA[i] = (wid * 128 + i * 64) * 8;
  }
  #pragma unroll
  for (int i = 0; i < 4; i++) {
    int ci = wid * 256 + i * 64 + lane;
    int P = ci * 16;
    int L = P ^ (((P >> 7) & 7) << 4);
    soffB[i] = (L >> 6) * K + ((L >> 4) & 3) * 8;
    ldsoB[i] = (wid * 256 + i * 64) * 8;
  }

  f32x4 acc[4][8] = {};

  auto stage = [&](int t, int b) {
    int kk = t * 32;
    #pragma unroll
    for (int i = 0; i < 2; i++)
      gload_lds16(A + (size_t)row0 * K + kk + soffA[i], &ldsA[b][ldsoA[i]]);
    #pragma unroll
    for (int i = 0; i < 4; i++)
      gload_lds16(Bt + (size_t)col0 * K + kk + soffB[i], &ldsB[b][ldsoB[i]]);
  };

  auto compute = [&](int b) {
    bf16x8 af[4], bfv[8];
    #pragma unroll
    for (int mi = 0; mi < 4; mi++) {
      int r = wm * 64 + mi * 16 + rl;
      int L = r * 64 + cg * 16;
      int P = L ^ (((L >> 7) & 7) << 4);
      af[mi] = *(const bf16x8*)&ldsA[b][P >> 1];
    }
    #pragma unroll
    for (int ni = 0; ni < 8; ni++) {
      int r = wn * 128 + ni * 16 + rl;
      int L = r * 64 + cg * 16;
      int P = L ^ (((L >> 7) & 7) << 4);
      bfv[ni] = *(const bf16x8*)&ldsB[b][P >> 1];
    }
    __builtin_amdgcn_s_setprio(1);
    #pragma unroll
    for (int mi = 0; mi < 4; mi++)
      #pragma unroll
      for (int ni = 0; ni < 8; ni++)
        acc[mi][ni] = __builtin_amdgcn_mfma_f32_16x16x32_bf16(af[mi], bfv[ni], acc[mi][ni], 0, 0, 0);
    __builtin_amdgcn_s_setprio(0);
  };

  stage(0, 0); stage(1, 1);
  int sb = 2, cb = 0;
  for (int t = 0; t < NT; ++t) {
    if (t < NT - 1) asm volatile("s_waitcnt vmcnt(6)" ::: "memory");
    else            asm volatile("s_waitcnt vmcnt(0)" ::: "memory");
    __builtin_amdgcn_s_barrier();
    __builtin_amdgcn_sched_barrier(0);
    if (t + 2 < NT) { stage(t + 2, sb); sb = (sb == 2) ? 0 : sb + 1; }
    compute(cb);
    cb = (cb == 2) ? 0 : cb + 1;
  }

  ushort_t* out = (ushort_t*)Cout;
  #pragma unroll
  for (int ni = 0; ni < 8; ni++) {
    int col = col0 + wn * 128 + ni * 16 + rl;
    float bv = bias[col];
    float sc = (EPI == 0 && col < 1024) ? 0.18033688011f : 1.0f;
    #pragma unroll
    for (int mi = 0; mi < 4; mi++) {
      int rowb = row0 + wm * 64 + mi * 16 + cg * 4;
      #pragma unroll
      for (int j = 0; j < 4; j++) {
        float v = acc[mi][ni][j] + bv;
        if (EPI == 1) v = fmaxf(v, 0.0f);
        if (EPI == 0) v *= sc;
        out[(size_t)(rowb + j) * N + col] = f2bf(v);
      }
    }
  }
}

// ---------------- GEMM 128x128, BK=32, 3-buffer LDS ring (48KB -> 3 blocks/CU) ----------------
// EPI: 2 = fp32 + bias + resid (fused); 3 = fp32 partial at Cout + s*M*N (split-K).
template <int EPI>
__global__ __launch_bounds__(256, 3) void gemm128_kernel(
    const ushort_t* __restrict__ A, const ushort_t* __restrict__ Bt,
    const float* __restrict__ bias, const float* __restrict__ resid,
    void* __restrict__ Cout, int M, int N, int K, int NTn, int Ksplit, int MTN) {
  __shared__ __align__(16) ushort_t lds[3][2][4096];  // [buf][A|B][8KB] = 48KB
  const int tid = threadIdx.x, lane = tid & 63, wid = tid >> 6;
  const int wm = wid >> 1, wn = wid & 1;
  const int rl = lane & 15, cg = lane >> 4;
  int nwg = gridDim.x;
  int q = nwg >> 3, rr = nwg & 7;
  int xcd = blockIdx.x & 7, idx = blockIdx.x >> 3;
  int wgid = (xcd < rr ? xcd * (q + 1) : rr * (q + 1) + (xcd - rr) * q) + idx;
  const int s = wgid / MTN;
  int rem = wgid - s * MTN;
  const int row0 = (rem / NTn) * 128, col0 = (rem - (rem / NTn) * NTn) * 128;
  const int k0 = s * Ksplit;
  const int NT = Ksplit / 32;

  int soff[2], ldso[2];
  #pragma unroll
  for (int i = 0; i < 2; i++) {
    int ci = wid * 128 + i * 64 + lane;
    int P = ci * 16;
    int L = P ^ (((P >> 7) & 7) << 4);
    int row = L >> 6, kc = (L >> 4) & 3;
    soff[i] = row * K + kc * 8;
    ldso[i] = (wid * 128 + i * 64) * 8;
  }

  f32x4 acc[4][4] = {};

  auto stage = [&](int t, int b) {
    int kk = k0 + t * 32;
    #pragma unroll
    for (int i = 0; i < 2; i++) {
      gload_lds16(A + (size_t)row0 * K + kk + soff[i], &lds[b][0][ldso[i]]);
      gload_lds16(Bt + (size_t)col0 * K + kk + soff[i], &lds[b][1][ldso[i]]);
    }
  };

  auto compute = [&](int b) {
    bf16x8 af[4], bfv[4];
    #pragma unroll
    for (int mi = 0; mi < 4; mi++) {
      int r = wm * 64 + mi * 16 + rl;
      int L = r * 64 + cg * 16;
      int P = L ^ (((L >> 7) & 7) << 4);
      af[mi] = *(const bf16x8*)&lds[b][0][P >> 1];
    }
    #pragma unroll
    for (int ni = 0; ni < 4; ni++) {
      int r = wn * 64 + ni * 16 + rl;
      int L = r * 64 + cg * 16;
      int P = L ^ (((L >> 7) & 7) << 4);
      bfv[ni] = *(const bf16x8*)&lds[b][1][P >> 1];
    }
    __builtin_amdgcn_s_setprio(1);
    #pragma unroll
    for (int mi = 0; mi < 4; mi++)
      #pragma unroll
      for (int ni = 0; ni < 4; ni++)
        acc[mi][ni] = __builtin_amdgcn_mfma_f32_16x16x32_bf16(af[mi], bfv[ni], acc[mi][ni], 0, 0, 0);
    __builtin_amdgcn_s_setprio(0);
  };

  stage(0, 0); stage(1, 1);
  int sb = 2, cb = 0;
  for (int t = 0; t < NT; ++t) {
    if (t < NT - 1) asm volatile("s_waitcnt vmcnt(4)" ::: "memory");
    else            asm volatile("s_waitcnt vmcnt(0)" ::: "memory");
    __builtin_amdgcn_s_barrier();
    __builtin_amdgcn_sched_barrier(0);
    if (t + 2 < NT) { stage(t + 2, sb); sb = (sb == 2) ? 0 : sb + 1; }
    compute(cb);
    cb = (cb == 2) ? 0 : cb + 1;
  }

  if (EPI == 2) {
    float* out = (float*)Cout;
    #pragma unroll
    for (int ni = 0; ni < 4; ni++) {
      int col = col0 + wn * 64 + ni * 16 + rl;
      float bv = bias[col];
      #pragma unroll
      for (int mi = 0; mi < 4; mi++) {
        int rowb = row0 + wm * 64 + mi * 16 + cg * 4;
        #pragma unroll
        for (int j = 0; j < 4; j++)
          out[(size_t)(rowb + j) * N + col] =
              acc[mi][ni][j] + bv + resid[(size_t)(rowb + j) * N + col];
      }
    }
  } else {
    float* out = (float*)Cout + (size_t)s * M * N;
    #pragma unroll
    for (int ni = 0; ni < 4; ni++) {
      int col = col0 + wn * 64 + ni * 16 + rl;
      #pragma unroll
      for (int mi = 0; mi < 4; mi++) {
        int rowb = row0 + wm * 64 + mi * 16 + cg * 4;
        #pragma unroll
        for (int j = 0; j < 4; j++)
          out[(size_t)(rowb + j) * N + col] = acc[mi][ni][j];
      }
    }
  }
}

// ---------------- split-K reduce: out = sum(partials) + bias + resid (fp32, N=1024) ----------------
__global__ __launch_bounds__(256) void reduce_kernel(
    const float* __restrict__ p, const float* __restrict__ bias,
    const float* __restrict__ resid, float* __restrict__ out,
    int S, size_t total4, size_t stride4) {
  const float4* p4 = (const float4*)p;
  const float4* r4 = (const float4*)resid;
  const float4* b4 = (const float4*)bias;
  float4* o4 = (float4*)out;
  for (size_t i = (size_t)blockIdx.x * 256 + threadIdx.x; i < total4;
       i += (size_t)gridDim.x * 256) {
    float4 a = r4[i];
    float4 bb = b4[i & 255];
    a.x += bb.x; a.y += bb.y; a.z += bb.z; a.w += bb.w;
    for (int s = 0; s < S; ++s) {
      float4 v = p4[(size_t)s * stride4 + i];
      a.x += v.x; a.y += v.y; a.z += v.z; a.w += v.w;
    }
    o4[i] = a;
  }
}

// ---------------- flash attention: swapped-QK^T 32x32 MFMA, in-register P, split-KV ----------------
// (round-15 structure; split s covers keys [s*1024, s*1024+1024).) Static-shift softmax
// (no max tracking) makes split-KV exact: O and l partials just sum across splits.
// Writes unnormalized fp32 O to Op[split] and per-q l to Lp[split].
__global__ __launch_bounds__(256) void attn_kernel(
    const ushort_t* __restrict__ qkv, const ushort_t* __restrict__ Vt,
    float* __restrict__ Op, float* __restrict__ Lp) {
  __shared__ __align__(16) ushort_t Kl[2][64 * 64];   // [key][d] chunk-XOR, 8KB each
  __shared__ __align__(16) ushort_t Vl[2][64 * 64];   // [d][key] chunk-XOR, 8KB each
  const int tid = threadIdx.x, lane = tid & 63, wid = tid >> 6;
  const int split = blockIdx.z;
  int bid = blockIdx.y * 16 + blockIdx.x;
  int w = (bid & 7) * 64 + (bid >> 3);
  const int bh = w >> 4, qt = w & 15;
  const int b = bh >> 4, h = bh & 15;
  const int q0w = qt * 128 + wid * 32;
  const int k31 = lane & 31, sg = lane >> 5, x7 = k31 & 7;
  const ushort_t* Qp = qkv + (size_t)b * SS * 3072 + h * 64;
  const ushort_t* Kp = Qp + 1024 + (size_t)split * 1024 * 3072;
  const ushort_t* Vg = Vt + (size_t)bh * 64 * SS + split * 1024;

  bf16x8 qf[4];
  {
    const ushort_t* qb = Qp + (size_t)(q0w + k31) * 3072 + sg * 8;
    #pragma unroll
    for (int dsl = 0; dsl < 4; dsl++)
      qf[dsl] = *(const bf16x8*)(qb + dsl * 16);
  }
  float lsum = 0.f;
  f32x16 o0 = {}, o1 = {};

  const int NT = 1024 / KVBLK;  // 16 tiles per split

  int ksrc[2], vsrc[2];
  #pragma unroll
  for (int i = 0; i < 2; i++) {
    int idx = wid * 128 + i * 64 + lane;
    int R = idx >> 3, c = idx & 7;
    ksrc[i] = R * 3072 + ((c ^ (R & 7)) * 8);
    vsrc[i] = R * SS + ((c ^ (R & 7)) * 8);
  }
  const int ldsb = wid * 1024;

  auto stageKV = [&](int buf, int t) {
    size_t kvK = (size_t)t * KVBLK * 3072;
    int kvV = t * KVBLK;
    gload_lds16(Kp + kvK + ksrc[0], &Kl[buf][ldsb]);
    gload_lds16(Kp + kvK + ksrc[1], &Kl[buf][ldsb + 512]);
    gload_lds16(Vg + kvV + vsrc[0], &Vl[buf][ldsb]);
    gload_lds16(Vg + kvV + vsrc[1], &Vl[buf][ldsb + 512]);
  };

  auto softmax_half = [&](const f32x16& s, bf16x8& paE, bf16x8& paO) {
    float pv[16];
    #pragma unroll
    for (int r = 0; r < 16; r++) pv[r] = __builtin_amdgcn_exp2f(s[r]);
    #pragma unroll
    for (int r = 0; r < 16; r++) lsum += pv[r];
    unsigned W[4][2];
    #pragma unroll
    for (int qd = 0; qd < 4; qd++) {
      asm("v_cvt_pk_bf16_f32 %0, %1, %2" : "=v"(W[qd][0]) : "v"(pv[4 * qd]), "v"(pv[4 * qd + 1]));
      asm("v_cvt_pk_bf16_f32 %0, %1, %2" : "=v"(W[qd][1]) : "v"(pv[4 * qd + 2]), "v"(pv[4 * qd + 3]));
    }
    unsigned a0 = W[1][0], b0 = W[0][0], a1 = W[1][1], b1 = W[0][1];
    asm("v_permlane32_swap_b32 %0, %1" : "+v"(a0), "+v"(b0));
    asm("v_permlane32_swap_b32 %0, %1" : "+v"(a1), "+v"(b1));
    paE = pack4w(b0, b1, a0, a1);
    unsigned a2 = W[3][0], b2 = W[2][0], a3 = W[3][1], b3 = W[2][1];
    asm("v_permlane32_swap_b32 %0, %1" : "+v"(a2), "+v"(b2));
    asm("v_permlane32_swap_b32 %0, %1" : "+v"(a3), "+v"(b3));
    paO = pack4w(b2, b3, a2, a3);
  };

  auto body = [&](int t, int cb) {
    __syncthreads();
    if (t + 1 < NT) stageKV(cb ^ 1, t + 1);

    f32x16 s0 = {}, s1 = {};
    #pragma unroll
    for (int dsl = 0; dsl < 4; dsl++) {
      int ch = ((dsl * 2 + sg) ^ x7) * 8;
      bf16x8 kf0 = *(const bf16x8*)(&Kl[cb][k31 * 64 + ch]);
      bf16x8 kf1 = *(const bf16x8*)(&Kl[cb][(32 + k31) * 64 + ch]);
      s0 = __builtin_amdgcn_mfma_f32_32x32x16_bf16(kf0, qf[dsl], s0, 0, 0, 0);
      s1 = __builtin_amdgcn_mfma_f32_32x32x16_bf16(kf1, qf[dsl], s1, 0, 0, 0);
    }
    bf16x8 pa[4];
    softmax_half(s0, pa[0], pa[1]);
    softmax_half(s1, pa[2], pa[3]);
    #pragma unroll
    for (int ks = 0; ks < 4; ks++) {
      int ch = ((2 * ks + sg) ^ x7) * 8;
      bf16x8 vf0 = *(const bf16x8*)(&Vl[cb][k31 * 64 + ch]);
      bf16x8 vf1 = *(const bf16x8*)(&Vl[cb][(32 + k31) * 64 + ch]);
      o0 = __builtin_amdgcn_mfma_f32_32x32x16_bf16(pa[ks], vf0, o0, 0, 0, 0);
      o1 = __builtin_amdgcn_mfma_f32_32x32x16_bf16(pa[ks], vf1, o1, 0, 0, 0);
    }
  };

  stageKV(0, 0);
  for (int t = 0; t < NT; t += 2) {
    body(t, 0);
    body(t + 1, 1);
  }

  // l partial: lane k31 holds q=k31's sum over its 32 keys; add partner half.
  float ltot = lsum + __shfl_xor(lsum, 32);
  if (lane < 32)
    Lp[(size_t)split * 32 * SS + bh * SS + q0w + lane] = ltot;

  float* Ob = Op + (size_t)split * MROWS * 1024;
  const int colb = h * 64 + k31;
  #pragma unroll
  for (int r = 0; r < 16; r++) {
    int qp = (r & 3) + 8 * (r >> 2) + 4 * sg;
    size_t row = (size_t)(b * SS + q0w + qp);
    Ob[row * 1024 + colb] = o0[r];
    Ob[row * 1024 + colb + 32] = o1[r];
  }
}

// ---------------- split-KV combine: ctx = (Oa+Ob) / (la+lb), bf16 ----------------
__global__ __launch_bounds__(256) void attn_combine_kernel(
    const float* __restrict__ Op, const float* __restrict__ Lp,
    ushort_t* __restrict__ ctx) {
  int row = blockIdx.x;          // 0..4095
  int tid = threadIdx.x;         // 0..255 (float4 per thread)
  int col = tid * 4;
  int b = row >> 11, q = row & 2047;
  int bh = b * 16 + (col >> 6);
  float l = Lp[bh * SS + q] + Lp[32 * SS + bh * SS + q];
  float rl = 1.0f / l;
  const float4 a = *(const float4*)(Op + (size_t)row * 1024 + col);
  const float4 c = *(const float4*)(Op + (size_t)MROWS * 1024 + (size_t)row * 1024 + col);
  ushort4 o;
  o.x = f2bf((a.x + c.x) * rl);
  o.y = f2bf((a.y + c.y) * rl);
  o.z = f2bf((a.z + c.z) * rl);
  o.w = f2bf((a.w + c.w) * rl);
  *(ushort4*)(ctx + (size_t)row * D_MODEL + col) = o;
}

extern "C" void kernel_launch(void* const* d_in, const int* in_sizes, int n_in,
                              void* d_out, int out_size, void* d_ws, size_t ws_size,
                              hipStream_t stream) {
  const float* x    = (const float*)d_in[0];
  const float* ln1w = (const float*)d_in[1];
  const float* ln1b = (const float*)d_in[2];
  const float* Wq   = (const float*)d_in[3];
  const float* bq   = (const float*)d_in[4];
  const float* Wk   = (const float*)d_in[5];
  const float* bk   = (const float*)d_in[6];
  const float* Wv   = (const float*)d_in[7];
  const float* bv   = (const float*)d_in[8];
  const float* Wo   = (const float*)d_in[9];
  const float* bo   = (const float*)d_in[10];
  const float* ln2w = (const float*)d_in[11];
  const float* ln2b = (const float*)d_in[12];
  const float* W1   = (const float*)d_in[13];
  const float* b1   = (const float*)d_in[14];
  const float* W2   = (const float*)d_in[15];
  const float* b2   = (const float*)d_in[16];

  char* ws = (char*)d_ws;
  size_t off = 0;
  auto alloc = [&](size_t bytes) {
    void* p = ws + off;
    off += (bytes + 255) & ~(size_t)255;
    return p;
  };
  ushort_t* Wt_qkv = (ushort_t*)alloc((size_t)3072 * 1024 * 2);
  ushort_t* Wt_o   = (ushort_t*)alloc((size_t)1024 * 1024 * 2);
  ushort_t* Wt_1   = (ushort_t*)alloc((size_t)4096 * 1024 * 2);
  ushort_t* Wt_2   = (ushort_t*)alloc((size_t)1024 * 4096 * 2);
  float*    bqkv   = (float*)alloc((size_t)3072 * 4);
  ushort_t* qkvb   = (ushort_t*)alloc((size_t)MROWS * 3072 * 2);  // 24 MB
  ushort_t* ctxb   = (ushort_t*)alloc((size_t)MROWS * 1024 * 2);  // 8 MB
  ushort_t* hbuf   = (ushort_t*)alloc((size_t)MROWS * 1024 * 2);
  float*    x2     = (float*)alloc((size_t)MROWS * 1024 * 4);
  ushort_t* Vtb    = (ushort_t*)alloc((size_t)BB * NH * 64 * SS * 2);  // 8 MB
  ushort_t* ff1    = qkvb;  // reuse qkv(24MB)+ctx(8MB) = 32MB for [4096][4096] bf16
  float*    outp   = (float*)d_out;

  // 32 MB buffer shared by attn O-partials (2 x 16MB) and later FFN2 split-K partials
  const size_t partial1 = (size_t)MROWS * 1024 * 4;  // 16 MB per split
  float* obuf = (float*)alloc(2 * partial1);
  float* lbuf = (float*)alloc((size_t)2 * 32 * SS * 4);  // 512 KB
  float* pbuf = obuf;

  dim3 tb(32, 8);
  transpose_cast4_kernel<<<dim3(32, 32, 4), tb, 0, stream>>>(Wq, Wk, Wv, Wo, Wt_qkv, Wt_o);
  transpose_cast_kernel<<<dim3(128, 32), tb, 0, stream>>>(W1, Wt_1, 1024, 4096);
  transpose_cast_kernel<<<dim3(32, 128), tb, 0, stream>>>(W2, Wt_2, 4096, 1024);
  biaspack_kernel<<<12, 256, 0, stream>>>(bq, bk, bv, bqkv);

  // LN1 -> h
  ln_bf16_kernel<<<MROWS, 256, 0, stream>>>(x, ln1w, ln1b, hbuf);
  // fused QKV GEMM: [4096,1024]x[1024,3072] -> bf16 (Q cols pre-scaled by Cs); 128x256 tiles
  gemm256w_kernel<0><<<dim3(32 * 12), 256, 0, stream>>>(
      hbuf, Wt_qkv, bqkv, qkvb, MROWS, 3072, 1024, 12);
  // V transpose -> Vt[bh][64][2048]
  vtrans_kernel<<<dim3(SS / 64, BB * NH), 256, 0, stream>>>(qkvb, Vtb);
  // attention: split-KV (2 splits), 1024 blocks total -> fp32 O/l partials
  attn_kernel<<<dim3(SS / 128, BB * NH, 2), 256, 0, stream>>>(qkvb, Vtb, obuf, lbuf);
  attn_combine_kernel<<<MROWS, 256, 0, stream>>>(obuf, lbuf, ctxb);
  // O-proj + bias + residual(x) -> x2 (fp32), fused
  gemm128_kernel<2><<<dim3(8 * 32), 256, 0, stream>>>(
      ctxb, Wt_o, bo, x, x2, MROWS, 1024, 1024, 8, 1024, 8 * 32);
  // LN2 -> h
  ln_bf16_kernel<<<MROWS, 256, 0, stream>>>(x2, ln2w, ln2b, hbuf);
  // FFN1 + relu -> ff1 (bf16); 128x256 tiles, 512 blocks = exact 2/CU
  gemm256w_kernel<1><<<dim3(32 * 16), 256, 0, stream>>>(
      hbuf, Wt_1, b1, ff1, MROWS, D_FF, 1024, 16);
  // FFN2: split-K=2 -> fp32 partials (reuses obuf); reduce adds bias b2 + resid x2 -> out
  gemm128_kernel<3><<<dim3(8 * 32 * 2), 256, 0, stream>>>(
      ff1, Wt_2, nullptr, nullptr, pbuf, MROWS, 1024, 4096, 8, 2048, 8 * 32);
  reduce_kernel<<<2048, 256, 0, stream>>>(pbuf, b2, x2, outp, 2,
      (size_t)MROWS * 1024 / 4, (size_t)MROWS * 1024 / 4);
}

// Round 18
// 230.767 us; speedup vs baseline: 1.0461x; 1.0461x over previous
//
#include <hip/hip_runtime.h>
#include <hip/hip_bf16.h>
#include <cstdint>
#include <cstddef>

typedef unsigned short ushort_t;
typedef __bf16 bf16x8 __attribute__((ext_vector_type(8)));
typedef float f32x4 __attribute__((ext_vector_type(4)));
typedef float f32x16 __attribute__((ext_vector_type(16)));

#define D_MODEL 1024
#define D_FF 4096
#define BB 2
#define SS 2048
#define NH 16
#define MROWS (BB * SS) /* 4096 */
#define KVBLK 64

__device__ __forceinline__ ushort_t f2bf(float f) {
  union { float f; unsigned u; } x; x.f = f;
  unsigned r = x.u + 0x7fffu + ((x.u >> 16) & 1u);
  return (ushort_t)(r >> 16);
}

__device__ __forceinline__ void gload_lds16(const void* g, void* l) {
  __builtin_amdgcn_global_load_lds((const __attribute__((address_space(1))) void*)g,
                                   (__attribute__((address_space(3))) void*)l, 16, 0, 0);
}

__device__ __forceinline__ bf16x8 pack4w(unsigned w0, unsigned w1, unsigned w2, unsigned w3) {
  union { unsigned u[4]; bf16x8 v; } t;
  t.u[0] = w0; t.u[1] = w1; t.u[2] = w2; t.u[3] = w3;
  return t.v;
}

// ---------------- LayerNorm (fp32 in -> bf16 out) ----------------
__global__ __launch_bounds__(256) void ln_bf16_kernel(
    const float* __restrict__ x, const float* __restrict__ w,
    const float* __restrict__ b, ushort_t* __restrict__ out) {
  int row = blockIdx.x;
  int tid = threadIdx.x;
  int lane = tid & 63, wid = tid >> 6;
  const float4 v = ((const float4*)(x + (size_t)row * D_MODEL))[tid];
  float s = v.x + v.y + v.z + v.w;
  __shared__ float red[8];
  #pragma unroll
  for (int o = 32; o > 0; o >>= 1) s += __shfl_down(s, o);
  if (lane == 0) red[wid] = s;
  __syncthreads();
  float mu = (red[0] + red[1] + red[2] + red[3]) * (1.0f / D_MODEL);
  float d0 = v.x - mu, d1 = v.y - mu, d2 = v.z - mu, d3 = v.w - mu;
  float sq = d0 * d0 + d1 * d1 + d2 * d2 + d3 * d3;
  #pragma unroll
  for (int o = 32; o > 0; o >>= 1) sq += __shfl_down(sq, o);
  if (lane == 0) red[4 + wid] = sq;
  __syncthreads();
  float var = (red[4] + red[5] + red[6] + red[7]) * (1.0f / D_MODEL);
  float rstd = rsqrtf(var + 1e-5f);
  const float4 wv = ((const float4*)w)[tid];
  const float4 bv = ((const float4*)b)[tid];
  ushort4 o4;
  o4.x = f2bf(d0 * rstd * wv.x + bv.x);
  o4.y = f2bf(d1 * rstd * wv.y + bv.y);
  o4.z = f2bf(d2 * rstd * wv.z + bv.z);
  o4.w = f2bf(d3 * rstd * wv.w + bv.w);
  ((ushort4*)(out + (size_t)row * D_MODEL))[tid] = o4;
}

// ---------------- transpose + cast: W[K][N] fp32 -> Wt[N][K] bf16 ----------------
__global__ __launch_bounds__(256) void transpose_cast_kernel(
    const float* __restrict__ W, ushort_t* __restrict__ Wt, int K, int N) {
  __shared__ float tile[32][33];
  int bx = blockIdx.x * 32;  // n
  int by = blockIdx.y * 32;  // k
  int tx = threadIdx.x, ty = threadIdx.y;  // 32 x 8
  #pragma unroll
  for (int i = 0; i < 32; i += 8)
    tile[ty + i][tx] = W[(size_t)(by + ty + i) * N + bx + tx];
  __syncthreads();
  #pragma unroll
  for (int i = 0; i < 32; i += 8)
    Wt[(size_t)(bx + ty + i) * K + by + tx] = f2bf(tile[tx][ty + i]);
}

// 4x 1024x1024 transposes in one launch (Wq,Wk,Wv -> Wt_qkv; Wo -> Wt_o)
__global__ __launch_bounds__(256) void transpose_cast4_kernel(
    const float* __restrict__ Wq, const float* __restrict__ Wk,
    const float* __restrict__ Wv, const float* __restrict__ Wo,
    ushort_t* __restrict__ Dqkv, ushort_t* __restrict__ Do_) {
  __shared__ float tile[32][33];
  int z = blockIdx.z;
  const float* W = (z == 0) ? Wq : (z == 1) ? Wk : (z == 2) ? Wv : Wo;
  ushort_t* Wt = (z < 3) ? (Dqkv + (size_t)z * 1024 * 1024) : Do_;
  int bx = blockIdx.x * 32;
  int by = blockIdx.y * 32;
  int tx = threadIdx.x, ty = threadIdx.y;
  #pragma unroll
  for (int i = 0; i < 32; i += 8)
    tile[ty + i][tx] = W[(size_t)(by + ty + i) * 1024 + bx + tx];
  __syncthreads();
  #pragma unroll
  for (int i = 0; i < 32; i += 8)
    Wt[(size_t)(bx + ty + i) * 1024 + by + tx] = f2bf(tile[tx][ty + i]);
}

// pack bq|bk|bv -> bqkv (3072 fp32)
__global__ __launch_bounds__(256) void biaspack_kernel(
    const float* __restrict__ bq, const float* __restrict__ bk,
    const float* __restrict__ bv, float* __restrict__ out) {
  int i = blockIdx.x * 256 + threadIdx.x;
  float v = (i < 1024) ? bq[i] : (i < 2048) ? bk[i - 1024] : bv[i - 2048];
  out[i] = v;
}

// ---------------- V transpose: qkv V-slice -> Vt[bh][64 d][SS keys] bf16 ----------------
__global__ __launch_bounds__(256) void vtrans_kernel(
    const ushort_t* __restrict__ qkv, ushort_t* __restrict__ Vt) {
  __shared__ __align__(16) ushort_t T[64 * 64];  // [key][d], chunk-XOR swizzled
  const int tid = threadIdx.x;
  const int bh = blockIdx.y, b = bh >> 4, h = bh & 15;
  const int kv0 = blockIdx.x * 64;
  const ushort_t* Vp = qkv + (size_t)b * SS * 3072 + 2048 + h * 64;
  #pragma unroll
  for (int i = 0; i < 2; i++) {
    int idx = tid * 2 + i;          // chunk index
    int key = idx >> 3, c = idx & 7;
    bf16x8 v = *(const bf16x8*)(Vp + (size_t)(kv0 + key) * 3072 + c * 8);
    *(bf16x8*)(T + key * 64 + ((c ^ (key & 7)) * 8)) = v;
  }
  __syncthreads();
  int d = tid >> 2, kb = tid & 3;
  ushort_t o[16];
  #pragma unroll
  for (int j = 0; j < 16; j++) {
    int key = kb * 16 + j;
    o[j] = T[key * 64 + (((d >> 3) ^ (key & 7)) * 8) + (d & 7)];
  }
  ushort_t* dst = Vt + (size_t)(bh * 64 + d) * SS + kv0 + kb * 16;
  *(bf16x8*)dst = *(bf16x8*)&o[0];
  *(bf16x8*)(dst + 8) = *(bf16x8*)&o[8];
}

// ---------------- GEMM 128x256, BK=32, 3-buffer LDS ring (72KB -> 2 blocks/CU) ----------------
// EPI: 0 = bf16 + bias (cols<1024 scaled by Cs for QKV); 1 = bf16 + bias + relu.
template <int EPI>
__global__ __launch_bounds__(256, 2) void gemm256w_kernel(
    const ushort_t* __restrict__ A, const ushort_t* __restrict__ Bt,
    const float* __restrict__ bias, void* __restrict__ Cout,
    int M, int N, int K, int NTn) {
  __shared__ __align__(16) ushort_t ldsA[3][4096];  // 8KB each
  __shared__ __align__(16) ushort_t ldsB[3][8192];  // 16KB each
  const int tid = threadIdx.x, lane = tid & 63, wid = tid >> 6;
  const int wm = wid >> 1, wn = wid & 1;
  const int rl = lane & 15, cg = lane >> 4;
  int nwg = gridDim.x;
  int q = nwg >> 3, rr = nwg & 7;
  int xcd = blockIdx.x & 7, idx = blockIdx.x >> 3;
  int wgid = (xcd < rr ? xcd * (q + 1) : rr * (q + 1) + (xcd - rr) * q) + idx;
  const int row0 = (wgid / NTn) * 128, col0 = (wgid - (wgid / NTn) * NTn) * 256;
  const int NT = K / 32;

  int soffA[2], ldsoA[2], soffB[4], ldsoB[4];
  #pragma unroll
  for (int i = 0; i < 2; i++) {
    int ci = wid * 128 + i * 64 + lane;
    int P = ci * 16;
    int L = P ^ (((P >> 7) & 7) << 4);
    soffA[i] = (L >> 6) * K + ((L >> 4) & 3) * 8;
    ldsoA[i] = (wid * 128 + i * 64) * 8;
  }
  #pragma unroll
  for (int i = 0; i < 4; i++) {
    int ci = wid * 256 + i * 64 + lane;
    int P = ci * 16;
    int L = P ^ (((P >> 7) & 7) << 4);
    soffB[i] = (L >> 6) * K + ((L >> 4) & 3) * 8;
    ldsoB[i] = (wid * 256 + i * 64) * 8;
  }

  f32x4 acc[4][8] = {};

  auto stage = [&](int t, int b) {
    int kk = t * 32;
    #pragma unroll
    for (int i = 0; i < 2; i++)
      gload_lds16(A + (size_t)row0 * K + kk + soffA[i], &ldsA[b][ldsoA[i]]);
    #pragma unroll
    for (int i = 0; i < 4; i++)
      gload_lds16(Bt + (size_t)col0 * K + kk + soffB[i], &ldsB[b][ldsoB[i]]);
  };

  auto compute = [&](int b) {
    bf16x8 af[4], bfv[8];
    #pragma unroll
    for (int mi = 0; mi < 4; mi++) {
      int r = wm * 64 + mi * 16 + rl;
      int L = r * 64 + cg * 16;
      int P = L ^ (((L >> 7) & 7) << 4);
      af[mi] = *(const bf16x8*)&ldsA[b][P >> 1];
    }
    #pragma unroll
    for (int ni = 0; ni < 8; ni++) {
      int r = wn * 128 + ni * 16 + rl;
      int L = r * 64 + cg * 16;
      int P = L ^ (((L >> 7) & 7) << 4);
      bfv[ni] = *(const bf16x8*)&ldsB[b][P >> 1];
    }
    __builtin_amdgcn_s_setprio(1);
    #pragma unroll
    for (int mi = 0; mi < 4; mi++)
      #pragma unroll
      for (int ni = 0; ni < 8; ni++)
        acc[mi][ni] = __builtin_amdgcn_mfma_f32_16x16x32_bf16(af[mi], bfv[ni], acc[mi][ni], 0, 0, 0);
    __builtin_amdgcn_s_setprio(0);
  };

  stage(0, 0); stage(1, 1);
  int sb = 2, cb = 0;
  for (int t = 0; t < NT; ++t) {
    if (t < NT - 1) asm volatile("s_waitcnt vmcnt(6)" ::: "memory");
    else            asm volatile("s_waitcnt vmcnt(0)" ::: "memory");
    __builtin_amdgcn_s_barrier();
    __builtin_amdgcn_sched_barrier(0);
    if (t + 2 < NT) { stage(t + 2, sb); sb = (sb == 2) ? 0 : sb + 1; }
    compute(cb);
    cb = (cb == 2) ? 0 : cb + 1;
  }

  ushort_t* out = (ushort_t*)Cout;
  #pragma unroll
  for (int ni = 0; ni < 8; ni++) {
    int col = col0 + wn * 128 + ni * 16 + rl;
    float bv = bias[col];
    float sc = (EPI == 0 && col < 1024) ? 0.18033688011f : 1.0f;
    #pragma unroll
    for (int mi = 0; mi < 4; mi++) {
      int rowb = row0 + wm * 64 + mi * 16 + cg * 4;
      #pragma unroll
      for (int j = 0; j < 4; j++) {
        float v = acc[mi][ni][j] + bv;
        if (EPI == 1) v = fmaxf(v, 0.0f);
        if (EPI == 0) v *= sc;
        out[(size_t)(rowb + j) * N + col] = f2bf(v);
      }
    }
  }
}

// ---------------- GEMM 128x128, BK=32, 3-buffer LDS ring (48KB -> 3 blocks/CU) ----------------
// EPI: 2 = fp32 + bias + resid (fused); 3 = fp32 partial at Cout + s*M*N (split-K).
template <int EPI>
__global__ __launch_bounds__(256, 3) void gemm128_kernel(
    const ushort_t* __restrict__ A, const ushort_t* __restrict__ Bt,
    const float* __restrict__ bias, const float* __restrict__ resid,
    void* __restrict__ Cout, int M, int N, int K, int NTn, int Ksplit, int MTN) {
  __shared__ __align__(16) ushort_t lds[3][2][4096];  // [buf][A|B][8KB] = 48KB
  const int tid = threadIdx.x, lane = tid & 63, wid = tid >> 6;
  const int wm = wid >> 1, wn = wid & 1;
  const int rl = lane & 15, cg = lane >> 4;
  int nwg = gridDim.x;
  int q = nwg >> 3, rr = nwg & 7;
  int xcd = blockIdx.x & 7, idx = blockIdx.x >> 3;
  int wgid = (xcd < rr ? xcd * (q + 1) : rr * (q + 1) + (xcd - rr) * q) + idx;
  const int s = wgid / MTN;
  int rem = wgid - s * MTN;
  const int row0 = (rem / NTn) * 128, col0 = (rem - (rem / NTn) * NTn) * 128;
  const int k0 = s * Ksplit;
  const int NT = Ksplit / 32;

  int soff[2], ldso[2];
  #pragma unroll
  for (int i = 0; i < 2; i++) {
    int ci = wid * 128 + i * 64 + lane;
    int P = ci * 16;
    int L = P ^ (((P >> 7) & 7) << 4);
    int row = L >> 6, kc = (L >> 4) & 3;
    soff[i] = row * K + kc * 8;
    ldso[i] = (wid * 128 + i * 64) * 8;
  }

  f32x4 acc[4][4] = {};

  auto stage = [&](int t, int b) {
    int kk = k0 + t * 32;
    #pragma unroll
    for (int i = 0; i < 2; i++) {
      gload_lds16(A + (size_t)row0 * K + kk + soff[i], &lds[b][0][ldso[i]]);
      gload_lds16(Bt + (size_t)col0 * K + kk + soff[i], &lds[b][1][ldso[i]]);
    }
  };

  auto compute = [&](int b) {
    bf16x8 af[4], bfv[4];
    #pragma unroll
    for (int mi = 0; mi < 4; mi++) {
      int r = wm * 64 + mi * 16 + rl;
      int L = r * 64 + cg * 16;
      int P = L ^ (((L >> 7) & 7) << 4);
      af[mi] = *(const bf16x8*)&lds[b][0][P >> 1];
    }
    #pragma unroll
    for (int ni = 0; ni < 4; ni++) {
      int r = wn * 64 + ni * 16 + rl;
      int L = r * 64 + cg * 16;
      int P = L ^ (((L >> 7) & 7) << 4);
      bfv[ni] = *(const bf16x8*)&lds[b][1][P >> 1];
    }
    __builtin_amdgcn_s_setprio(1);
    #pragma unroll
    for (int mi = 0; mi < 4; mi++)
      #pragma unroll
      for (int ni = 0; ni < 4; ni++)
        acc[mi][ni] = __builtin_amdgcn_mfma_f32_16x16x32_bf16(af[mi], bfv[ni], acc[mi][ni], 0, 0, 0);
    __builtin_amdgcn_s_setprio(0);
  };

  stage(0, 0); stage(1, 1);
  int sb = 2, cb = 0;
  for (int t = 0; t < NT; ++t) {
    if (t < NT - 1) asm volatile("s_waitcnt vmcnt(4)" ::: "memory");
    else            asm volatile("s_waitcnt vmcnt(0)" ::: "memory");
    __builtin_amdgcn_s_barrier();
    __builtin_amdgcn_sched_barrier(0);
    if (t + 2 < NT) { stage(t + 2, sb); sb = (sb == 2) ? 0 : sb + 1; }
    compute(cb);
    cb = (cb == 2) ? 0 : cb + 1;
  }

  if (EPI == 2) {
    float* out = (float*)Cout;
    #pragma unroll
    for (int ni = 0; ni < 4; ni++) {
      int col = col0 + wn * 64 + ni * 16 + rl;
      float bv = bias[col];
      #pragma unroll
      for (int mi = 0; mi < 4; mi++) {
        int rowb = row0 + wm * 64 + mi * 16 + cg * 4;
        #pragma unroll
        for (int j = 0; j < 4; j++)
          out[(size_t)(rowb + j) * N + col] =
              acc[mi][ni][j] + bv + resid[(size_t)(rowb + j) * N + col];
      }
    }
  } else {
    float* out = (float*)Cout + (size_t)s * M * N;
    #pragma unroll
    for (int ni = 0; ni < 4; ni++) {
      int col = col0 + wn * 64 + ni * 16 + rl;
      #pragma unroll
      for (int mi = 0; mi < 4; mi++) {
        int rowb = row0 + wm * 64 + mi * 16 + cg * 4;
        #pragma unroll
        for (int j = 0; j < 4; j++)
          out[(size_t)(rowb + j) * N + col] = acc[mi][ni][j];
      }
    }
  }
}

// ---------------- split-K reduce: out = sum(partials) + bias + resid (fp32, N=1024) ----------------
__global__ __launch_bounds__(256) void reduce_kernel(
    const float* __restrict__ p, const float* __restrict__ bias,
    const float* __restrict__ resid, float* __restrict__ out,
    int S, size_t total4, size_t stride4) {
  const float4* p4 = (const float4*)p;
  const float4* r4 = (const float4*)resid;
  const float4* b4 = (const float4*)bias;
  float4* o4 = (float4*)out;
  for (size_t i = (size_t)blockIdx.x * 256 + threadIdx.x; i < total4;
       i += (size_t)gridDim.x * 256) {
    float4 a = r4[i];
    float4 bb = b4[i & 255];
    a.x += bb.x; a.y += bb.y; a.z += bb.z; a.w += bb.w;
    for (int s = 0; s < S; ++s) {
      float4 v = p4[(size_t)s * stride4 + i];
      a.x += v.x; a.y += v.y; a.z += v.z; a.w += v.w;
    }
    o4[i] = a;
  }
}

// ---------------- flash attention: swapped-QK^T 32x32 MFMA, in-register P ----------------
// (round-15 structure.) Conflict-fix: LDS chunk swizzle f(R) = (R ^ (R>>3)) & 7 on BOTH
// sides (staging source + reads) so the 4 lanes sharing R&7 hit distinct bank groups.
__global__ __launch_bounds__(256) void attn_kernel(
    const ushort_t* __restrict__ qkv, const ushort_t* __restrict__ Vt,
    ushort_t* __restrict__ ctx) {
  __shared__ __align__(16) ushort_t Kl[2][64 * 64];   // [key][d] chunk-XOR, 8KB each
  __shared__ __align__(16) ushort_t Vl[2][64 * 64];   // [d][key] chunk-XOR, 8KB each
  __shared__ float Lt[4][32];
  const int tid = threadIdx.x, lane = tid & 63, wid = tid >> 6;
  int bid = blockIdx.y * 16 + blockIdx.x;
  int w = (bid & 7) * 64 + (bid >> 3);
  const int bh = w >> 4, qt = w & 15;
  const int b = bh >> 4, h = bh & 15;
  const int q0w = qt * 128 + wid * 32;
  const int k31 = lane & 31, sg = lane >> 5;
  const int f0 = (k31 ^ (k31 >> 3)) & 7;           // swizzle for row k31
  const int f1 = (k31 ^ ((k31 >> 3) + 4)) & 7;     // swizzle for row 32+k31
  const ushort_t* Qp = qkv + (size_t)b * SS * 3072 + h * 64;
  const ushort_t* Kp = Qp + 1024;
  const ushort_t* Vg = Vt + (size_t)bh * 64 * SS;

  bf16x8 qf[4];
  {
    const ushort_t* qb = Qp + (size_t)(q0w + k31) * 3072 + sg * 8;
    #pragma unroll
    for (int dsl = 0; dsl < 4; dsl++)
      qf[dsl] = *(const bf16x8*)(qb + dsl * 16);
  }
  float lsum = 0.f;
  f32x16 o0 = {}, o1 = {};

  const int NT = SS / KVBLK;

  int ksrc[2], vsrc[2];
  #pragma unroll
  for (int i = 0; i < 2; i++) {
    int idx = wid * 128 + i * 64 + lane;
    int R = idx >> 3, c = idx & 7;
    int fR = (R ^ (R >> 3)) & 7;
    ksrc[i] = R * 3072 + ((c ^ fR) * 8);
    vsrc[i] = R * SS + ((c ^ fR) * 8);
  }
  const int ldsb = wid * 1024;

  auto stageKV = [&](int buf, int t) {
    size_t kvK = (size_t)t * KVBLK * 3072;
    int kvV = t * KVBLK;
    gload_lds16(Kp + kvK + ksrc[0], &Kl[buf][ldsb]);
    gload_lds16(Kp + kvK + ksrc[1], &Kl[buf][ldsb + 512]);
    gload_lds16(Vg + kvV + vsrc[0], &Vl[buf][ldsb]);
    gload_lds16(Vg + kvV + vsrc[1], &Vl[buf][ldsb + 512]);
  };

  auto softmax_half = [&](const f32x16& s, bf16x8& paE, bf16x8& paO) {
    float pv[16];
    #pragma unroll
    for (int r = 0; r < 16; r++) pv[r] = __builtin_amdgcn_exp2f(s[r]);
    #pragma unroll
    for (int r = 0; r < 16; r++) lsum += pv[r];
    unsigned W[4][2];
    #pragma unroll
    for (int qd = 0; qd < 4; qd++) {
      asm("v_cvt_pk_bf16_f32 %0, %1, %2" : "=v"(W[qd][0]) : "v"(pv[4 * qd]), "v"(pv[4 * qd + 1]));
      asm("v_cvt_pk_bf16_f32 %0, %1, %2" : "=v"(W[qd][1]) : "v"(pv[4 * qd + 2]), "v"(pv[4 * qd + 3]));
    }
    unsigned a0 = W[1][0], b0 = W[0][0], a1 = W[1][1], b1 = W[0][1];
    asm("v_permlane32_swap_b32 %0, %1" : "+v"(a0), "+v"(b0));
    asm("v_permlane32_swap_b32 %0, %1" : "+v"(a1), "+v"(b1));
    paE = pack4w(b0, b1, a0, a1);
    unsigned a2 = W[3][0], b2 = W[2][0], a3 = W[3][1], b3 = W[2][1];
    asm("v_permlane32_swap_b32 %0, %1" : "+v"(a2), "+v"(b2));
    asm("v_permlane32_swap_b32 %0, %1" : "+v"(a3), "+v"(b3));
    paO = pack4w(b2, b3, a2, a3);
  };

  auto body = [&](int t, int cb) {
    __syncthreads();
    if (t + 1 < NT) stageKV(cb ^ 1, t + 1);

    f32x16 s0 = {}, s1 = {};
    #pragma unroll
    for (int dsl = 0; dsl < 4; dsl++) {
      int chl = dsl * 2 + sg;
      bf16x8 kf0 = *(const bf16x8*)(&Kl[cb][k31 * 64 + ((chl ^ f0) * 8)]);
      bf16x8 kf1 = *(const bf16x8*)(&Kl[cb][(32 + k31) * 64 + ((chl ^ f1) * 8)]);
      s0 = __builtin_amdgcn_mfma_f32_32x32x16_bf16(kf0, qf[dsl], s0, 0, 0, 0);
      s1 = __builtin_amdgcn_mfma_f32_32x32x16_bf16(kf1, qf[dsl], s1, 0, 0, 0);
    }
    bf16x8 pa[4];
    softmax_half(s0, pa[0], pa[1]);
    softmax_half(s1, pa[2], pa[3]);
    #pragma unroll
    for (int ks = 0; ks < 4; ks++) {
      int chl = 2 * ks + sg;
      bf16x8 vf0 = *(const bf16x8*)(&Vl[cb][k31 * 64 + ((chl ^ f0) * 8)]);
      bf16x8 vf1 = *(const bf16x8*)(&Vl[cb][(32 + k31) * 64 + ((chl ^ f1) * 8)]);
      o0 = __builtin_amdgcn_mfma_f32_32x32x16_bf16(pa[ks], vf0, o0, 0, 0, 0);
      o1 = __builtin_amdgcn_mfma_f32_32x32x16_bf16(pa[ks], vf1, o1, 0, 0, 0);
    }
  };

  stageKV(0, 0);
  for (int t = 0; t < NT; t += 2) {
    body(t, 0);
    body(t + 1, 1);
  }

  float ltot = lsum + __shfl_xor(lsum, 32);
  if (lane < 32) Lt[wid][lane] = ltot;
  asm volatile("s_waitcnt lgkmcnt(0)" ::: "memory");
  __builtin_amdgcn_sched_barrier(0);

  const int colb = h * 64 + k31;
  #pragma unroll
  for (int r = 0; r < 16; r++) {
    int qp = (r & 3) + 8 * (r >> 2) + 4 * sg;
    float rlq = 1.0f / Lt[wid][qp];
    size_t row = (size_t)(b * SS + q0w + qp);
    ctx[row * D_MODEL + colb] = f2bf(o0[r] * rlq);
    ctx[row * D_MODEL + colb + 32] = f2bf(o1[r] * rlq);
  }
}

extern "C" void kernel_launch(void* const* d_in, const int* in_sizes, int n_in,
                              void* d_out, int out_size, void* d_ws, size_t ws_size,
                              hipStream_t stream) {
  const float* x    = (const float*)d_in[0];
  const float* ln1w = (const float*)d_in[1];
  const float* ln1b = (const float*)d_in[2];
  const float* Wq   = (const float*)d_in[3];
  const float* bq   = (const float*)d_in[4];
  const float* Wk   = (const float*)d_in[5];
  const float* bk   = (const float*)d_in[6];
  const float* Wv   = (const float*)d_in[7];
  const float* bv   = (const float*)d_in[8];
  const float* Wo   = (const float*)d_in[9];
  const float* bo   = (const float*)d_in[10];
  const float* ln2w = (const float*)d_in[11];
  const float* ln2b = (const float*)d_in[12];
  const float* W1   = (const float*)d_in[13];
  const float* b1   = (const float*)d_in[14];
  const float* W2   = (const float*)d_in[15];
  const float* b2   = (const float*)d_in[16];

  char* ws = (char*)d_ws;
  size_t off = 0;
  auto alloc = [&](size_t bytes) {
    void* p = ws + off;
    off += (bytes + 255) & ~(size_t)255;
    return p;
  };
  ushort_t* Wt_qkv = (ushort_t*)alloc((size_t)3072 * 1024 * 2);
  ushort_t* Wt_o   = (ushort_t*)alloc((size_t)1024 * 1024 * 2);
  ushort_t* Wt_1   = (ushort_t*)alloc((size_t)4096 * 1024 * 2);
  ushort_t* Wt_2   = (ushort_t*)alloc((size_t)1024 * 4096 * 2);
  float*    bqkv   = (float*)alloc((size_t)3072 * 4);
  ushort_t* qkvb   = (ushort_t*)alloc((size_t)MROWS * 3072 * 2);  // 24 MB
  ushort_t* ctxb   = (ushort_t*)alloc((size_t)MROWS * 1024 * 2);  // 8 MB
  ushort_t* hbuf   = (ushort_t*)alloc((size_t)MROWS * 1024 * 2);
  float*    x2     = (float*)alloc((size_t)MROWS * 1024 * 4);
  ushort_t* Vtb    = (ushort_t*)alloc((size_t)BB * NH * 64 * SS * 2);  // 8 MB
  ushort_t* ff1    = qkvb;  // reuse qkv(24MB)+ctx(8MB) = 32MB for [4096][4096] bf16
  float*    outp   = (float*)d_out;

  // split-K=2 partials for FFN2 (32 MB); fallback to fused if no room
  const size_t partial1 = (size_t)MROWS * 1024 * 4;  // 16 MB per split
  int S = (ws_size - off >= 2 * partial1 + 256) ? 2 : 1;
  float* pbuf = (S == 2) ? (float*)alloc(2 * partial1) : nullptr;

  dim3 tb(32, 8);
  transpose_cast4_kernel<<<dim3(32, 32, 4), tb, 0, stream>>>(Wq, Wk, Wv, Wo, Wt_qkv, Wt_o);
  transpose_cast_kernel<<<dim3(128, 32), tb, 0, stream>>>(W1, Wt_1, 1024, 4096);
  transpose_cast_kernel<<<dim3(32, 128), tb, 0, stream>>>(W2, Wt_2, 4096, 1024);
  biaspack_kernel<<<12, 256, 0, stream>>>(bq, bk, bv, bqkv);

  // LN1 -> h
  ln_bf16_kernel<<<MROWS, 256, 0, stream>>>(x, ln1w, ln1b, hbuf);
  // fused QKV GEMM: [4096,1024]x[1024,3072] -> bf16 (Q cols pre-scaled by Cs); 128x256 tiles
  gemm256w_kernel<0><<<dim3(32 * 12), 256, 0, stream>>>(
      hbuf, Wt_qkv, bqkv, qkvb, MROWS, 3072, 1024, 12);
  // V transpose -> Vt[bh][64][2048]
  vtrans_kernel<<<dim3(SS / 64, BB * NH), 256, 0, stream>>>(qkvb, Vtb);
  // attention: 128 q/block, 512 blocks
  attn_kernel<<<dim3(SS / 128, BB * NH), 256, 0, stream>>>(qkvb, Vtb, ctxb);
  // O-proj + bias + residual(x) -> x2 (fp32), fused
  gemm128_kernel<2><<<dim3(8 * 32), 256, 0, stream>>>(
      ctxb, Wt_o, bo, x, x2, MROWS, 1024, 1024, 8, 1024, 8 * 32);
  // LN2 -> h
  ln_bf16_kernel<<<MROWS, 256, 0, stream>>>(x2, ln2w, ln2b, hbuf);
  // FFN1 + relu -> ff1 (bf16); 128x256 tiles, 512 blocks = exact 2/CU
  gemm256w_kernel<1><<<dim3(32 * 16), 256, 0, stream>>>(
      hbuf, Wt_1, b1, ff1, MROWS, D_FF, 1024, 16);
  // FFN2: split-K=2 -> fp32 partials; reduce adds bias b2 + resid x2 -> out
  if (S == 2) {
    gemm128_kernel<3><<<dim3(8 * 32 * 2), 256, 0, stream>>>(
        ff1, Wt_2, nullptr, nullptr, pbuf, MROWS, 1024, 4096, 8, 2048, 8 * 32);
    reduce_kernel<<<2048, 256, 0, stream>>>(pbuf, b2, x2, outp, 2,
        (size_t)MROWS * 1024 / 4, (size_t)MROWS * 1024 / 4);
  } else {
    gemm128_kernel<2><<<dim3(8 * 32), 256, 0, stream>>>(
        ff1, Wt_2, b2, x2, outp, MROWS, 1024, 4096, 8, 4096, 8 * 32);
  }
}

// Round 19
// 224.724 us; speedup vs baseline: 1.0742x; 1.0269x over previous
//
#include <hip/hip_runtime.h>
#include <hip/hip_bf16.h>
#include <cstdint>
#include <cstddef>

typedef unsigned short ushort_t;
typedef __bf16 bf16x8 __attribute__((ext_vector_type(8)));
typedef float f32x4 __attribute__((ext_vector_type(4)));
typedef float f32x16 __attribute__((ext_vector_type(16)));

#define D_MODEL 1024
#define D_FF 4096
#define BB 2
#define SS 2048
#define NH 16
#define MROWS (BB * SS) /* 4096 */
#define KVBLK 64

__device__ __forceinline__ ushort_t f2bf(float f) {
  union { float f; unsigned u; } x; x.f = f;
  unsigned r = x.u + 0x7fffu + ((x.u >> 16) & 1u);
  return (ushort_t)(r >> 16);
}

__device__ __forceinline__ void gload_lds16(const void* g, void* l) {
  __builtin_amdgcn_global_load_lds((const __attribute__((address_space(1))) void*)g,
                                   (__attribute__((address_space(3))) void*)l, 16, 0, 0);
}

__device__ __forceinline__ bf16x8 pack4w(unsigned w0, unsigned w1, unsigned w2, unsigned w3) {
  union { unsigned u[4]; bf16x8 v; } t;
  t.u[0] = w0; t.u[1] = w1; t.u[2] = w2; t.u[3] = w3;
  return t.v;
}

// ---------------- LayerNorm (fp32 in -> bf16 out) ----------------
__global__ __launch_bounds__(256) void ln_bf16_kernel(
    const float* __restrict__ x, const float* __restrict__ w,
    const float* __restrict__ b, ushort_t* __restrict__ out) {
  int row = blockIdx.x;
  int tid = threadIdx.x;
  int lane = tid & 63, wid = tid >> 6;
  const float4 v = ((const float4*)(x + (size_t)row * D_MODEL))[tid];
  float s = v.x + v.y + v.z + v.w;
  __shared__ float red[8];
  #pragma unroll
  for (int o = 32; o > 0; o >>= 1) s += __shfl_down(s, o);
  if (lane == 0) red[wid] = s;
  __syncthreads();
  float mu = (red[0] + red[1] + red[2] + red[3]) * (1.0f / D_MODEL);
  float d0 = v.x - mu, d1 = v.y - mu, d2 = v.z - mu, d3 = v.w - mu;
  float sq = d0 * d0 + d1 * d1 + d2 * d2 + d3 * d3;
  #pragma unroll
  for (int o = 32; o > 0; o >>= 1) sq += __shfl_down(sq, o);
  if (lane == 0) red[4 + wid] = sq;
  __syncthreads();
  float var = (red[4] + red[5] + red[6] + red[7]) * (1.0f / D_MODEL);
  float rstd = rsqrtf(var + 1e-5f);
  const float4 wv = ((const float4*)w)[tid];
  const float4 bv = ((const float4*)b)[tid];
  ushort4 o4;
  o4.x = f2bf(d0 * rstd * wv.x + bv.x);
  o4.y = f2bf(d1 * rstd * wv.y + bv.y);
  o4.z = f2bf(d2 * rstd * wv.z + bv.z);
  o4.w = f2bf(d3 * rstd * wv.w + bv.w);
  ((ushort4*)(out + (size_t)row * D_MODEL))[tid] = o4;
}

// ---------------- unified prep: 6 transposes (fp32 -> bf16, W^T) + bias pack ----------------
// blocks 0..4095:   Wq|Wk|Wv|Wo (1024x1024 each, 1024 tile-blocks each)
// blocks 4096..8191: W1 (K=1024, N=4096)
// blocks 8192..12287: W2 (K=4096, N=1024)
// blocks 12288..12299: bias pack bq|bk|bv -> bqkv
__global__ __launch_bounds__(256) void prep_kernel(
    const float* __restrict__ Wq, const float* __restrict__ Wk,
    const float* __restrict__ Wv, const float* __restrict__ Wo,
    const float* __restrict__ W1, const float* __restrict__ W2,
    const float* __restrict__ bq, const float* __restrict__ bk,
    const float* __restrict__ bv,
    ushort_t* __restrict__ Dqkv, ushort_t* __restrict__ Do_,
    ushort_t* __restrict__ D1, ushort_t* __restrict__ D2,
    float* __restrict__ bqkv) {
  const int id = blockIdx.x;
  const int tx = threadIdx.x, ty = threadIdx.y;  // 32 x 8
  if (id >= 12288) {
    int i = (id - 12288) * 256 + ty * 32 + tx;
    float v = (i < 1024) ? bq[i] : (i < 2048) ? bk[i - 1024] : bv[i - 2048];
    bqkv[i] = v;
    return;
  }
  __shared__ float tile[32][33];
  const float* W;
  ushort_t* Wt;
  int K, N, bx, by;
  if (id < 4096) {
    int z = id >> 10, t = id & 1023;
    W = (z == 0) ? Wq : (z == 1) ? Wk : (z == 2) ? Wv : Wo;
    Wt = (z < 3) ? (Dqkv + (size_t)z * 1024 * 1024) : Do_;
    K = 1024; N = 1024; bx = (t & 31) * 32; by = (t >> 5) * 32;
  } else if (id < 8192) {
    int t = id - 4096;
    W = W1; Wt = D1; K = 1024; N = 4096;
    bx = (t & 127) * 32; by = (t >> 7) * 32;
  } else {
    int t = id - 8192;
    W = W2; Wt = D2; K = 4096; N = 1024;
    bx = (t & 31) * 32; by = (t >> 5) * 32;
  }
  #pragma unroll
  for (int i = 0; i < 32; i += 8)
    tile[ty + i][tx] = W[(size_t)(by + ty + i) * N + bx + tx];
  __syncthreads();
  #pragma unroll
  for (int i = 0; i < 32; i += 8)
    Wt[(size_t)(bx + ty + i) * K + by + tx] = f2bf(tile[tx][ty + i]);
}

// ---------------- V transpose: qkv V-slice -> Vt[bh][64 d][SS keys] bf16 ----------------
__global__ __launch_bounds__(256) void vtrans_kernel(
    const ushort_t* __restrict__ qkv, ushort_t* __restrict__ Vt) {
  __shared__ __align__(16) ushort_t T[64 * 64];  // [key][d], chunk-XOR swizzled
  const int tid = threadIdx.x;
  const int bh = blockIdx.y, b = bh >> 4, h = bh & 15;
  const int kv0 = blockIdx.x * 64;
  const ushort_t* Vp = qkv + (size_t)b * SS * 3072 + 2048 + h * 64;
  #pragma unroll
  for (int i = 0; i < 2; i++) {
    int idx = tid * 2 + i;          // chunk index
    int key = idx >> 3, c = idx & 7;
    bf16x8 v = *(const bf16x8*)(Vp + (size_t)(kv0 + key) * 3072 + c * 8);
    *(bf16x8*)(T + key * 64 + ((c ^ (key & 7)) * 8)) = v;
  }
  __syncthreads();
  int d = tid >> 2, kb = tid & 3;
  ushort_t o[16];
  #pragma unroll
  for (int j = 0; j < 16; j++) {
    int key = kb * 16 + j;
    o[j] = T[key * 64 + (((d >> 3) ^ (key & 7)) * 8) + (d & 7)];
  }
  ushort_t* dst = Vt + (size_t)(bh * 64 + d) * SS + kv0 + kb * 16;
  *(bf16x8*)dst = *(bf16x8*)&o[0];
  *(bf16x8*)(dst + 8) = *(bf16x8*)&o[8];
}

// ---------------- GEMM 128x256, BK=32, 3-buffer LDS ring (72KB -> 2 blocks/CU) ----------------
// EPI: 0 = bf16 + bias (cols<1024 scaled by Cs for QKV); 1 = bf16 + bias + relu.
template <int EPI>
__global__ __launch_bounds__(256, 2) void gemm256w_kernel(
    const ushort_t* __restrict__ A, const ushort_t* __restrict__ Bt,
    const float* __restrict__ bias, void* __restrict__ Cout,
    int M, int N, int K, int NTn) {
  __shared__ __align__(16) ushort_t ldsA[3][4096];  // 8KB each
  __shared__ __align__(16) ushort_t ldsB[3][8192];  // 16KB each
  const int tid = threadIdx.x, lane = tid & 63, wid = tid >> 6;
  const int wm = wid >> 1, wn = wid & 1;
  const int rl = lane & 15, cg = lane >> 4;
  int nwg = gridDim.x;
  int q = nwg >> 3, rr = nwg & 7;
  int xcd = blockIdx.x & 7, idx = blockIdx.x >> 3;
  int wgid = (xcd < rr ? xcd * (q + 1) : rr * (q + 1) + (xcd - rr) * q) + idx;
  const int row0 = (wgid / NTn) * 128, col0 = (wgid - (wgid / NTn) * NTn) * 256;
  const int NT = K / 32;

  int soffA[2], ldsoA[2], soffB[4], ldsoB[4];
  #pragma unroll
  for (int i = 0; i < 2; i++) {
    int ci = wid * 128 + i * 64 + lane;
    int P = ci * 16;
    int L = P ^ (((P >> 7) & 7) << 4);
    soffA[i] = (L >> 6) * K + ((L >> 4) & 3) * 8;
    ldsoA[i] = (wid * 128 + i * 64) * 8;
  }
  #pragma unroll
  for (int i = 0; i < 4; i++) {
    int ci = wid * 256 + i * 64 + lane;
    int P = ci * 16;
    int L = P ^ (((P >> 7) & 7) << 4);
    soffB[i] = (L >> 6) * K + ((L >> 4) & 3) * 8;
    ldsoB[i] = (wid * 256 + i * 64) * 8;
  }

  f32x4 acc[4][8] = {};

  auto stage = [&](int t, int b) {
    int kk = t * 32;
    #pragma unroll
    for (int i = 0; i < 2; i++)
      gload_lds16(A + (size_t)row0 * K + kk + soffA[i], &ldsA[b][ldsoA[i]]);
    #pragma unroll
    for (int i = 0; i < 4; i++)
      gload_lds16(Bt + (size_t)col0 * K + kk + soffB[i], &ldsB[b][ldsoB[i]]);
  };

  auto compute = [&](int b) {
    bf16x8 af[4], bfv[8];
    #pragma unroll
    for (int mi = 0; mi < 4; mi++) {
      int r = wm * 64 + mi * 16 + rl;
      int L = r * 64 + cg * 16;
      int P = L ^ (((L >> 7) & 7) << 4);
      af[mi] = *(const bf16x8*)&ldsA[b][P >> 1];
    }
    #pragma unroll
    for (int ni = 0; ni < 8; ni++) {
      int r = wn * 128 + ni * 16 + rl;
      int L = r * 64 + cg * 16;
      int P = L ^ (((L >> 7) & 7) << 4);
      bfv[ni] = *(const bf16x8*)&ldsB[b][P >> 1];
    }
    __builtin_amdgcn_s_setprio(1);
    #pragma unroll
    for (int mi = 0; mi < 4; mi++)
      #pragma unroll
      for (int ni = 0; ni < 8; ni++)
        acc[mi][ni] = __builtin_amdgcn_mfma_f32_16x16x32_bf16(af[mi], bfv[ni], acc[mi][ni], 0, 0, 0);
    __builtin_amdgcn_s_setprio(0);
  };

  stage(0, 0); stage(1, 1);
  int sb = 2, cb = 0;
  for (int t = 0; t < NT; ++t) {
    if (t < NT - 1) asm volatile("s_waitcnt vmcnt(6)" ::: "memory");
    else            asm volatile("s_waitcnt vmcnt(0)" ::: "memory");
    __builtin_amdgcn_s_barrier();
    __builtin_amdgcn_sched_barrier(0);
    if (t + 2 < NT) { stage(t + 2, sb); sb = (sb == 2) ? 0 : sb + 1; }
    compute(cb);
    cb = (cb == 2) ? 0 : cb + 1;
  }

  ushort_t* out = (ushort_t*)Cout;
  #pragma unroll
  for (int ni = 0; ni < 8; ni++) {
    int col = col0 + wn * 128 + ni * 16 + rl;
    float bv = bias[col];
    float sc = (EPI == 0 && col < 1024) ? 0.18033688011f : 1.0f;
    #pragma unroll
    for (int mi = 0; mi < 4; mi++) {
      int rowb = row0 + wm * 64 + mi * 16 + cg * 4;
      #pragma unroll
      for (int j = 0; j < 4; j++) {
        float v = acc[mi][ni][j] + bv;
        if (EPI == 1) v = fmaxf(v, 0.0f);
        if (EPI == 0) v *= sc;
        out[(size_t)(rowb + j) * N + col] = f2bf(v);
      }
    }
  }
}

// ---------------- GEMM 128x128, BK=32, 3-buffer LDS ring (48KB -> 3 blocks/CU) ----------------
// EPI: 2 = fp32 + bias + resid (fused); 3 = fp32 partial at Cout + s*M*N (split-K).
template <int EPI>
__global__ __launch_bounds__(256, 3) void gemm128_kernel(
    const ushort_t* __restrict__ A, const ushort_t* __restrict__ Bt,
    const float* __restrict__ bias, const float* __restrict__ resid,
    void* __restrict__ Cout, int M, int N, int K, int NTn, int Ksplit, int MTN) {
  __shared__ __align__(16) ushort_t lds[3][2][4096];  // [buf][A|B][8KB] = 48KB
  const int tid = threadIdx.x, lane = tid & 63, wid = tid >> 6;
  const int wm = wid >> 1, wn = wid & 1;
  const int rl = lane & 15, cg = lane >> 4;
  int nwg = gridDim.x;
  int q = nwg >> 3, rr = nwg & 7;
  int xcd = blockIdx.x & 7, idx = blockIdx.x >> 3;
  int wgid = (xcd < rr ? xcd * (q + 1) : rr * (q + 1) + (xcd - rr) * q) + idx;
  const int s = wgid / MTN;
  int rem = wgid - s * MTN;
  const int row0 = (rem / NTn) * 128, col0 = (rem - (rem / NTn) * NTn) * 128;
  const int k0 = s * Ksplit;
  const int NT = Ksplit / 32;

  int soff[2], ldso[2];
  #pragma unroll
  for (int i = 0; i < 2; i++) {
    int ci = wid * 128 + i * 64 + lane;
    int P = ci * 16;
    int L = P ^ (((P >> 7) & 7) << 4);
    int row = L >> 6, kc = (L >> 4) & 3;
    soff[i] = row * K + kc * 8;
    ldso[i] = (wid * 128 + i * 64) * 8;
  }

  f32x4 acc[4][4] = {};

  auto stage = [&](int t, int b) {
    int kk = k0 + t * 32;
    #pragma unroll
    for (int i = 0; i < 2; i++) {
      gload_lds16(A + (size_t)row0 * K + kk + soff[i], &lds[b][0][ldso[i]]);
      gload_lds16(Bt + (size_t)col0 * K + kk + soff[i], &lds[b][1][ldso[i]]);
    }
  };

  auto compute = [&](int b) {
    bf16x8 af[4], bfv[4];
    #pragma unroll
    for (int mi = 0; mi < 4; mi++) {
      int r = wm * 64 + mi * 16 + rl;
      int L = r * 64 + cg * 16;
      int P = L ^ (((L >> 7) & 7) << 4);
      af[mi] = *(const bf16x8*)&lds[b][0][P >> 1];
    }
    #pragma unroll
    for (int ni = 0; ni < 4; ni++) {
      int r = wn * 64 + ni * 16 + rl;
      int L = r * 64 + cg * 16;
      int P = L ^ (((L >> 7) & 7) << 4);
      bfv[ni] = *(const bf16x8*)&lds[b][1][P >> 1];
    }
    __builtin_amdgcn_s_setprio(1);
    #pragma unroll
    for (int mi = 0; mi < 4; mi++)
      #pragma unroll
      for (int ni = 0; ni < 4; ni++)
        acc[mi][ni] = __builtin_amdgcn_mfma_f32_16x16x32_bf16(af[mi], bfv[ni], acc[mi][ni], 0, 0, 0);
    __builtin_amdgcn_s_setprio(0);
  };

  stage(0, 0); stage(1, 1);
  int sb = 2, cb = 0;
  for (int t = 0; t < NT; ++t) {
    if (t < NT - 1) asm volatile("s_waitcnt vmcnt(4)" ::: "memory");
    else            asm volatile("s_waitcnt vmcnt(0)" ::: "memory");
    __builtin_amdgcn_s_barrier();
    __builtin_amdgcn_sched_barrier(0);
    if (t + 2 < NT) { stage(t + 2, sb); sb = (sb == 2) ? 0 : sb + 1; }
    compute(cb);
    cb = (cb == 2) ? 0 : cb + 1;
  }

  if (EPI == 2) {
    float* out = (float*)Cout;
    #pragma unroll
    for (int ni = 0; ni < 4; ni++) {
      int col = col0 + wn * 64 + ni * 16 + rl;
      float bv = bias[col];
      #pragma unroll
      for (int mi = 0; mi < 4; mi++) {
        int rowb = row0 + wm * 64 + mi * 16 + cg * 4;
        #pragma unroll
        for (int j = 0; j < 4; j++)
          out[(size_t)(rowb + j) * N + col] =
              acc[mi][ni][j] + bv + resid[(size_t)(rowb + j) * N + col];
      }
    }
  } else {
    float* out = (float*)Cout + (size_t)s * M * N;
    #pragma unroll
    for (int ni = 0; ni < 4; ni++) {
      int col = col0 + wn * 64 + ni * 16 + rl;
      #pragma unroll
      for (int mi = 0; mi < 4; mi++) {
        int rowb = row0 + wm * 64 + mi * 16 + cg * 4;
        #pragma unroll
        for (int j = 0; j < 4; j++)
          out[(size_t)(rowb + j) * N + col] = acc[mi][ni][j];
      }
    }
  }
}

// ---------------- split-K reduce: out = sum(partials) + bias + resid (fp32, N=1024) ----------------
__global__ __launch_bounds__(256) void reduce_kernel(
    const float* __restrict__ p, const float* __restrict__ bias,
    const float* __restrict__ resid, float* __restrict__ out,
    int S, size_t total4, size_t stride4) {
  const float4* p4 = (const float4*)p;
  const float4* r4 = (const float4*)resid;
  const float4* b4 = (const float4*)bias;
  float4* o4 = (float4*)out;
  for (size_t i = (size_t)blockIdx.x * 256 + threadIdx.x; i < total4;
       i += (size_t)gridDim.x * 256) {
    float4 a = r4[i];
    float4 bb = b4[i & 255];
    a.x += bb.x; a.y += bb.y; a.z += bb.z; a.w += bb.w;
    for (int s = 0; s < S; ++s) {
      float4 v = p4[(size_t)s * stride4 + i];
      a.x += v.x; a.y += v.y; a.z += v.z; a.w += v.w;
    }
    o4[i] = a;
  }
}

// ---------------- flash attention: swapped-QK^T 32x32 MFMA, in-register P ----------------
// Conflict-free LDS chunk swizzle f(R) = (R ^ (R>>3)) & 7 on BOTH sides.
__global__ __launch_bounds__(256) void attn_kernel(
    const ushort_t* __restrict__ qkv, const ushort_t* __restrict__ Vt,
    ushort_t* __restrict__ ctx) {
  __shared__ __align__(16) ushort_t Kl[2][64 * 64];   // [key][d] chunk-XOR, 8KB each
  __shared__ __align__(16) ushort_t Vl[2][64 * 64];   // [d][key] chunk-XOR, 8KB each
  __shared__ float Lt[4][32];
  const int tid = threadIdx.x, lane = tid & 63, wid = tid >> 6;
  int bid = blockIdx.y * 16 + blockIdx.x;
  int w = (bid & 7) * 64 + (bid >> 3);
  const int bh = w >> 4, qt = w & 15;
  const int b = bh >> 4, h = bh & 15;
  const int q0w = qt * 128 + wid * 32;
  const int k31 = lane & 31, sg = lane >> 5;
  const int f0 = (k31 ^ (k31 >> 3)) & 7;           // swizzle for row k31
  const int f1 = (k31 ^ ((k31 >> 3) + 4)) & 7;     // swizzle for row 32+k31
  const ushort_t* Qp = qkv + (size_t)b * SS * 3072 + h * 64;
  const ushort_t* Kp = Qp + 1024;
  const ushort_t* Vg = Vt + (size_t)bh * 64 * SS;

  bf16x8 qf[4];
  {
    const ushort_t* qb = Qp + (size_t)(q0w + k31) * 3072 + sg * 8;
    #pragma unroll
    for (int dsl = 0; dsl < 4; dsl++)
      qf[dsl] = *(const bf16x8*)(qb + dsl * 16);
  }
  float lsum = 0.f;
  f32x16 o0 = {}, o1 = {};

  const int NT = SS / KVBLK;

  int ksrc[2], vsrc[2];
  #pragma unroll
  for (int i = 0; i < 2; i++) {
    int idx = wid * 128 + i * 64 + lane;
    int R = idx >> 3, c = idx & 7;
    int fR = (R ^ (R >> 3)) & 7;
    ksrc[i] = R * 3072 + ((c ^ fR) * 8);
    vsrc[i] = R * SS + ((c ^ fR) * 8);
  }
  const int ldsb = wid * 1024;

  auto stageKV = [&](int buf, int t) {
    size_t kvK = (size_t)t * KVBLK * 3072;
    int kvV = t * KVBLK;
    gload_lds16(Kp + kvK + ksrc[0], &Kl[buf][ldsb]);
    gload_lds16(Kp + kvK + ksrc[1], &Kl[buf][ldsb + 512]);
    gload_lds16(Vg + kvV + vsrc[0], &Vl[buf][ldsb]);
    gload_lds16(Vg + kvV + vsrc[1], &Vl[buf][ldsb + 512]);
  };

  auto softmax_half = [&](const f32x16& s, bf16x8& paE, bf16x8& paO) {
    float pv[16];
    #pragma unroll
    for (int r = 0; r < 16; r++) pv[r] = __builtin_amdgcn_exp2f(s[r]);
    #pragma unroll
    for (int r = 0; r < 16; r++) lsum += pv[r];
    unsigned W[4][2];
    #pragma unroll
    for (int qd = 0; qd < 4; qd++) {
      asm("v_cvt_pk_bf16_f32 %0, %1, %2" : "=v"(W[qd][0]) : "v"(pv[4 * qd]), "v"(pv[4 * qd + 1]));
      asm("v_cvt_pk_bf16_f32 %0, %1, %2" : "=v"(W[qd][1]) : "v"(pv[4 * qd + 2]), "v"(pv[4 * qd + 3]));
    }
    unsigned a0 = W[1][0], b0 = W[0][0], a1 = W[1][1], b1 = W[0][1];
    asm("v_permlane32_swap_b32 %0, %1" : "+v"(a0), "+v"(b0));
    asm("v_permlane32_swap_b32 %0, %1" : "+v"(a1), "+v"(b1));
    paE = pack4w(b0, b1, a0, a1);
    unsigned a2 = W[3][0], b2 = W[2][0], a3 = W[3][1], b3 = W[2][1];
    asm("v_permlane32_swap_b32 %0, %1" : "+v"(a2), "+v"(b2));
    asm("v_permlane32_swap_b32 %0, %1" : "+v"(a3), "+v"(b3));
    paO = pack4w(b2, b3, a2, a3);
  };

  auto body = [&](int t, int cb) {
    __syncthreads();
    if (t + 1 < NT) stageKV(cb ^ 1, t + 1);

    f32x16 s0 = {}, s1 = {};
    #pragma unroll
    for (int dsl = 0; dsl < 4; dsl++) {
      int chl = dsl * 2 + sg;
      bf16x8 kf0 = *(const bf16x8*)(&Kl[cb][k31 * 64 + ((chl ^ f0) * 8)]);
      bf16x8 kf1 = *(const bf16x8*)(&Kl[cb][(32 + k31) * 64 + ((chl ^ f1) * 8)]);
      s0 = __builtin_amdgcn_mfma_f32_32x32x16_bf16(kf0, qf[dsl], s0, 0, 0, 0);
      s1 = __builtin_amdgcn_mfma_f32_32x32x16_bf16(kf1, qf[dsl], s1, 0, 0, 0);
    }
    bf16x8 pa[4];
    softmax_half(s0, pa[0], pa[1]);
    softmax_half(s1, pa[2], pa[3]);
    #pragma unroll
    for (int ks = 0; ks < 4; ks++) {
      int chl = 2 * ks + sg;
      bf16x8 vf0 = *(const bf16x8*)(&Vl[cb][k31 * 64 + ((chl ^ f0) * 8)]);
      bf16x8 vf1 = *(const bf16x8*)(&Vl[cb][(32 + k31) * 64 + ((chl ^ f1) * 8)]);
      o0 = __builtin_amdgcn_mfma_f32_32x32x16_bf16(pa[ks], vf0, o0, 0, 0, 0);
      o1 = __builtin_amdgcn_mfma_f32_32x32x16_bf16(pa[ks], vf1, o1, 0, 0, 0);
    }
  };

  stageKV(0, 0);
  for (int t = 0; t < NT; t += 2) {
    body(t, 0);
    body(t + 1, 1);
  }

  float ltot = lsum + __shfl_xor(lsum, 32);
  if (lane < 32) Lt[wid][lane] = ltot;
  asm volatile("s_waitcnt lgkmcnt(0)" ::: "memory");
  __builtin_amdgcn_sched_barrier(0);

  const int colb = h * 64 + k31;
  #pragma unroll
  for (int r = 0; r < 16; r++) {
    int qp = (r & 3) + 8 * (r >> 2) + 4 * sg;
    float rlq = 1.0f / Lt[wid][qp];
    size_t row = (size_t)(b * SS + q0w + qp);
    ctx[row * D_MODEL + colb] = f2bf(o0[r] * rlq);
    ctx[row * D_MODEL + colb + 32] = f2bf(o1[r] * rlq);
  }
}

extern "C" void kernel_launch(void* const* d_in, const int* in_sizes, int n_in,
                              void* d_out, int out_size, void* d_ws, size_t ws_size,
                              hipStream_t stream) {
  const float* x    = (const float*)d_in[0];
  const float* ln1w = (const float*)d_in[1];
  const float* ln1b = (const float*)d_in[2];
  const float* Wq   = (const float*)d_in[3];
  const float* bq   = (const float*)d_in[4];
  const float* Wk   = (const float*)d_in[5];
  const float* bk   = (const float*)d_in[6];
  const float* Wv   = (const float*)d_in[7];
  const float* bv   = (const float*)d_in[8];
  const float* Wo   = (const float*)d_in[9];
  const float* bo   = (const float*)d_in[10];
  const float* ln2w = (const float*)d_in[11];
  const float* ln2b = (const float*)d_in[12];
  const float* W1   = (const float*)d_in[13];
  const float* b1   = (const float*)d_in[14];
  const float* W2   = (const float*)d_in[15];
  const float* b2   = (const float*)d_in[16];

  char* ws = (char*)d_ws;
  size_t off = 0;
  auto alloc = [&](size_t bytes) {
    void* p = ws + off;
    off += (bytes + 255) & ~(size_t)255;
    return p;
  };
  ushort_t* Wt_qkv = (ushort_t*)alloc((size_t)3072 * 1024 * 2);
  ushort_t* Wt_o   = (ushort_t*)alloc((size_t)1024 * 1024 * 2);
  ushort_t* Wt_1   = (ushort_t*)alloc((size_t)4096 * 1024 * 2);
  ushort_t* Wt_2   = (ushort_t*)alloc((size_t)1024 * 4096 * 2);
  float*    bqkv   = (float*)alloc((size_t)3072 * 4);
  ushort_t* qkvb   = (ushort_t*)alloc((size_t)MROWS * 3072 * 2);  // 24 MB
  ushort_t* ctxb   = (ushort_t*)alloc((size_t)MROWS * 1024 * 2);  // 8 MB
  ushort_t* hbuf   = (ushort_t*)alloc((size_t)MROWS * 1024 * 2);
  float*    x2     = (float*)alloc((size_t)MROWS * 1024 * 4);
  ushort_t* Vtb    = (ushort_t*)alloc((size_t)BB * NH * 64 * SS * 2);  // 8 MB
  ushort_t* ff1    = qkvb;  // reuse qkv(24MB)+ctx(8MB) = 32MB for [4096][4096] bf16
  float*    outp   = (float*)d_out;

  // split-K=2 partials for FFN2 (32 MB); fallback to fused if no room
  const size_t partial1 = (size_t)MROWS * 1024 * 4;  // 16 MB per split
  int S = (ws_size - off >= 2 * partial1 + 256) ? 2 : 1;
  float* pbuf = (S == 2) ? (float*)alloc(2 * partial1) : nullptr;

  // unified prep: all weight transposes + bias pack in one launch
  prep_kernel<<<dim3(12300), dim3(32, 8), 0, stream>>>(
      Wq, Wk, Wv, Wo, W1, W2, bq, bk, bv, Wt_qkv, Wt_o, Wt_1, Wt_2, bqkv);

  // LN1 -> h
  ln_bf16_kernel<<<MROWS, 256, 0, stream>>>(x, ln1w, ln1b, hbuf);
  // fused QKV GEMM: [4096,1024]x[1024,3072] -> bf16 (Q cols pre-scaled by Cs); 128x256 tiles
  gemm256w_kernel<0><<<dim3(32 * 12), 256, 0, stream>>>(
      hbuf, Wt_qkv, bqkv, qkvb, MROWS, 3072, 1024, 12);
  // V transpose -> Vt[bh][64][2048]
  vtrans_kernel<<<dim3(SS / 64, BB * NH), 256, 0, stream>>>(qkvb, Vtb);
  // attention: 128 q/block, 512 blocks
  attn_kernel<<<dim3(SS / 128, BB * NH), 256, 0, stream>>>(qkvb, Vtb, ctxb);
  // O-proj + bias + residual(x) -> x2 (fp32), fused
  gemm128_kernel<2><<<dim3(8 * 32), 256, 0, stream>>>(
      ctxb, Wt_o, bo, x, x2, MROWS, 1024, 1024, 8, 1024, 8 * 32);
  // LN2 -> h
  ln_bf16_kernel<<<MROWS, 256, 0, stream>>>(x2, ln2w, ln2b, hbuf);
  // FFN1 + relu -> ff1 (bf16); 128x256 tiles, 512 blocks = exact 2/CU
  gemm256w_kernel<1><<<dim3(32 * 16), 256, 0, stream>>>(
      hbuf, Wt_1, b1, ff1, MROWS, D_FF, 1024, 16);
  // FFN2: split-K=2 -> fp32 partials; reduce adds bias b2 + resid x2 -> out
  if (S == 2) {
    gemm128_kernel<3><<<dim3(8 * 32 * 2), 256, 0, stream>>>(
        ff1, Wt_2, nullptr, nullptr, pbuf, MROWS, 1024, 4096, 8, 2048, 8 * 32);
    reduce_kernel<<<2048, 256, 0, stream>>>(pbuf, b2, x2, outp, 2,
        (size_t)MROWS * 1024 / 4, (size_t)MROWS * 1024 / 4);
  } else {
    gemm128_kernel<2><<<dim3(8 * 32), 256, 0, stream>>>(
        ff1, Wt_2, b2, x2, outp, MROWS, 1024, 4096, 8, 4096, 8 * 32);
  }
}

// Round 20
// 221.684 us; speedup vs baseline: 1.0889x; 1.0137x over previous
//
#include <hip/hip_runtime.h>
#include <hip/hip_bf16.h>
#include <cstdint>
#include <cstddef>

typedef unsigned short ushort_t;
typedef __bf16 bf16x8 __attribute__((ext_vector_type(8)));
typedef float f32x4 __attribute__((ext_vector_type(4)));
typedef float f32x16 __attribute__((ext_vector_type(16)));

#define D_MODEL 1024
#define D_FF 4096
#define BB 2
#define SS 2048
#define NH 16
#define MROWS (BB * SS) /* 4096 */
#define KVBLK 64

__device__ __forceinline__ ushort_t f2bf(float f) {
  union { float f; unsigned u; } x; x.f = f;
  unsigned r = x.u + 0x7fffu + ((x.u >> 16) & 1u);
  return (ushort_t)(r >> 16);
}

__device__ __forceinline__ void gload_lds16(const void* g, void* l) {
  __builtin_amdgcn_global_load_lds((const __attribute__((address_space(1))) void*)g,
                                   (__attribute__((address_space(3))) void*)l, 16, 0, 0);
}

__device__ __forceinline__ bf16x8 pack4w(unsigned w0, unsigned w1, unsigned w2, unsigned w3) {
  union { unsigned u[4]; bf16x8 v; } t;
  t.u[0] = w0; t.u[1] = w1; t.u[2] = w2; t.u[3] = w3;
  return t.v;
}

// ---------------- LayerNorm (fp32 in -> bf16 out) ----------------
__global__ __launch_bounds__(256) void ln_bf16_kernel(
    const float* __restrict__ x, const float* __restrict__ w,
    const float* __restrict__ b, ushort_t* __restrict__ out) {
  int row = blockIdx.x;
  int tid = threadIdx.x;
  int lane = tid & 63, wid = tid >> 6;
  const float4 v = ((const float4*)(x + (size_t)row * D_MODEL))[tid];
  float s = v.x + v.y + v.z + v.w;
  __shared__ float red[8];
  #pragma unroll
  for (int o = 32; o > 0; o >>= 1) s += __shfl_down(s, o);
  if (lane == 0) red[wid] = s;
  __syncthreads();
  float mu = (red[0] + red[1] + red[2] + red[3]) * (1.0f / D_MODEL);
  float d0 = v.x - mu, d1 = v.y - mu, d2 = v.z - mu, d3 = v.w - mu;
  float sq = d0 * d0 + d1 * d1 + d2 * d2 + d3 * d3;
  #pragma unroll
  for (int o = 32; o > 0; o >>= 1) sq += __shfl_down(sq, o);
  if (lane == 0) red[4 + wid] = sq;
  __syncthreads();
  float var = (red[4] + red[5] + red[6] + red[7]) * (1.0f / D_MODEL);
  float rstd = rsqrtf(var + 1e-5f);
  const float4 wv = ((const float4*)w)[tid];
  const float4 bv = ((const float4*)b)[tid];
  ushort4 o4;
  o4.x = f2bf(d0 * rstd * wv.x + bv.x);
  o4.y = f2bf(d1 * rstd * wv.y + bv.y);
  o4.z = f2bf(d2 * rstd * wv.z + bv.z);
  o4.w = f2bf(d3 * rstd * wv.w + bv.w);
  ((ushort4*)(out + (size_t)row * D_MODEL))[tid] = o4;
}

// ---------------- unified prep: 6 transposes (fp32 -> bf16, W^T) + bias pack ----------------
__global__ __launch_bounds__(256) void prep_kernel(
    const float* __restrict__ Wq, const float* __restrict__ Wk,
    const float* __restrict__ Wv, const float* __restrict__ Wo,
    const float* __restrict__ W1, const float* __restrict__ W2,
    const float* __restrict__ bq, const float* __restrict__ bk,
    const float* __restrict__ bv,
    ushort_t* __restrict__ Dqkv, ushort_t* __restrict__ Do_,
    ushort_t* __restrict__ D1, ushort_t* __restrict__ D2,
    float* __restrict__ bqkv) {
  const int id = blockIdx.x;
  const int tx = threadIdx.x, ty = threadIdx.y;  // 32 x 8
  if (id >= 12288) {
    int i = (id - 12288) * 256 + ty * 32 + tx;
    float v = (i < 1024) ? bq[i] : (i < 2048) ? bk[i - 1024] : bv[i - 2048];
    bqkv[i] = v;
    return;
  }
  __shared__ float tile[32][33];
  const float* W;
  ushort_t* Wt;
  int K, N, bx, by;
  if (id < 4096) {
    int z = id >> 10, t = id & 1023;
    W = (z == 0) ? Wq : (z == 1) ? Wk : (z == 2) ? Wv : Wo;
    Wt = (z < 3) ? (Dqkv + (size_t)z * 1024 * 1024) : Do_;
    K = 1024; N = 1024; bx = (t & 31) * 32; by = (t >> 5) * 32;
  } else if (id < 8192) {
    int t = id - 4096;
    W = W1; Wt = D1; K = 1024; N = 4096;
    bx = (t & 127) * 32; by = (t >> 7) * 32;
  } else {
    int t = id - 8192;
    W = W2; Wt = D2; K = 4096; N = 1024;
    bx = (t & 31) * 32; by = (t >> 5) * 32;
  }
  #pragma unroll
  for (int i = 0; i < 32; i += 8)
    tile[ty + i][tx] = W[(size_t)(by + ty + i) * N + bx + tx];
  __syncthreads();
  #pragma unroll
  for (int i = 0; i < 32; i += 8)
    Wt[(size_t)(bx + ty + i) * K + by + tx] = f2bf(tile[tx][ty + i]);
}

// ---------------- GEMM 128x256, BK=32, 3-buffer LDS ring (72KB -> 2 blocks/CU) ----------------
// EPI: 0 = QKV: bf16 + bias, Q cols scaled by Cs; V col-tiles (col0>=2048) are written
//      TRANSPOSED directly to Vt[bh][64][2048] (vtrans fused into the epilogue);
//      1 = bf16 + bias + relu.
template <int EPI>
__global__ __launch_bounds__(256, 2) void gemm256w_kernel(
    const ushort_t* __restrict__ A, const ushort_t* __restrict__ Bt,
    const float* __restrict__ bias, void* __restrict__ Cout,
    ushort_t* __restrict__ Vt, int M, int N, int K, int NTn) {
  __shared__ __align__(16) ushort_t ldsA[3][4096];  // 8KB each
  __shared__ __align__(16) ushort_t ldsB[3][8192];  // 16KB each
  const int tid = threadIdx.x, lane = tid & 63, wid = tid >> 6;
  const int wm = wid >> 1, wn = wid & 1;
  const int rl = lane & 15, cg = lane >> 4;
  int nwg = gridDim.x;
  int q = nwg >> 3, rr = nwg & 7;
  int xcd = blockIdx.x & 7, idx = blockIdx.x >> 3;
  int wgid = (xcd < rr ? xcd * (q + 1) : rr * (q + 1) + (xcd - rr) * q) + idx;
  const int row0 = (wgid / NTn) * 128, col0 = (wgid - (wgid / NTn) * NTn) * 256;
  const int NT = K / 32;

  int soffA[2], ldsoA[2], soffB[4], ldsoB[4];
  #pragma unroll
  for (int i = 0; i < 2; i++) {
    int ci = wid * 128 + i * 64 + lane;
    int P = ci * 16;
    int L = P ^ (((P >> 7) & 7) << 4);
    soffA[i] = (L >> 6) * K + ((L >> 4) & 3) * 8;
    ldsoA[i] = (wid * 128 + i * 64) * 8;
  }
  #pragma unroll
  for (int i = 0; i < 4; i++) {
    int ci = wid * 256 + i * 64 + lane;
    int P = ci * 16;
    int L = P ^ (((P >> 7) & 7) << 4);
    soffB[i] = (L >> 6) * K + ((L >> 4) & 3) * 8;
    ldsoB[i] = (wid * 256 + i * 64) * 8;
  }

  f32x4 acc[4][8] = {};

  auto stage = [&](int t, int b) {
    int kk = t * 32;
    #pragma unroll
    for (int i = 0; i < 2; i++)
      gload_lds16(A + (size_t)row0 * K + kk + soffA[i], &ldsA[b][ldsoA[i]]);
    #pragma unroll
    for (int i = 0; i < 4; i++)
      gload_lds16(Bt + (size_t)col0 * K + kk + soffB[i], &ldsB[b][ldsoB[i]]);
  };

  auto compute = [&](int b) {
    bf16x8 af[4], bfv[8];
    #pragma unroll
    for (int mi = 0; mi < 4; mi++) {
      int r = wm * 64 + mi * 16 + rl;
      int L = r * 64 + cg * 16;
      int P = L ^ (((L >> 7) & 7) << 4);
      af[mi] = *(const bf16x8*)&ldsA[b][P >> 1];
    }
    #pragma unroll
    for (int ni = 0; ni < 8; ni++) {
      int r = wn * 128 + ni * 16 + rl;
      int L = r * 64 + cg * 16;
      int P = L ^ (((L >> 7) & 7) << 4);
      bfv[ni] = *(const bf16x8*)&ldsB[b][P >> 1];
    }
    __builtin_amdgcn_s_setprio(1);
    #pragma unroll
    for (int mi = 0; mi < 4; mi++)
      #pragma unroll
      for (int ni = 0; ni < 8; ni++)
        acc[mi][ni] = __builtin_amdgcn_mfma_f32_16x16x32_bf16(af[mi], bfv[ni], acc[mi][ni], 0, 0, 0);
    __builtin_amdgcn_s_setprio(0);
  };

  stage(0, 0); stage(1, 1);
  int sb = 2, cb = 0;
  for (int t = 0; t < NT; ++t) {
    if (t < NT - 1) asm volatile("s_waitcnt vmcnt(6)" ::: "memory");
    else            asm volatile("s_waitcnt vmcnt(0)" ::: "memory");
    __builtin_amdgcn_s_barrier();
    __builtin_amdgcn_sched_barrier(0);
    if (t + 2 < NT) { stage(t + 2, sb); sb = (sb == 2) ? 0 : sb + 1; }
    compute(cb);
    cb = (cb == 2) ? 0 : cb + 1;
  }

  if (EPI == 0 && col0 >= 2048) {
    // V col-tile: write transposed into Vt[bh][d][key]; 4 consecutive keys pack to 8B.
    const int bb = row0 >> 11;                 // batch (block-constant: 128 | 2048)
    const int keyb = (row0 & 2047) + wm * 64;  // key base for this wave
    #pragma unroll
    for (int ni = 0; ni < 8; ni++) {
      int col = col0 + wn * 128 + ni * 16 + rl;
      float bv = bias[col];
      int vcol = col - 2048;
      ushort_t* drow = Vt + ((size_t)(bb * 16 + (vcol >> 6)) * 64 + (vcol & 63)) * SS;
      #pragma unroll
      for (int mi = 0; mi < 4; mi++) {
        int key0 = keyb + mi * 16 + cg * 4;
        ushort4 pk;
        pk.x = f2bf(acc[mi][ni][0] + bv);
        pk.y = f2bf(acc[mi][ni][1] + bv);
        pk.z = f2bf(acc[mi][ni][2] + bv);
        pk.w = f2bf(acc[mi][ni][3] + bv);
        *(ushort4*)(drow + key0) = pk;
      }
    }
  } else {
    ushort_t* out = (ushort_t*)Cout;
    #pragma unroll
    for (int ni = 0; ni < 8; ni++) {
      int col = col0 + wn * 128 + ni * 16 + rl;
      float bv = bias[col];
      float sc = (EPI == 0 && col < 1024) ? 0.18033688011f : 1.0f;
      #pragma unroll
      for (int mi = 0; mi < 4; mi++) {
        int rowb = row0 + wm * 64 + mi * 16 + cg * 4;
        #pragma unroll
        for (int j = 0; j < 4; j++) {
          float v = acc[mi][ni][j] + bv;
          if (EPI == 1) v = fmaxf(v, 0.0f);
          if (EPI == 0) v *= sc;
          out[(size_t)(rowb + j) * N + col] = f2bf(v);
        }
      }
    }
  }
}

// ---------------- GEMM 128x128, BK=32, 3-buffer LDS ring (48KB -> 3 blocks/CU) ----------------
// EPI: 2 = fp32 + bias + resid (fused); 3 = fp32 partial at Cout + s*M*N (split-K).
template <int EPI>
__global__ __launch_bounds__(256, 3) void gemm128_kernel(
    const ushort_t* __restrict__ A, const ushort_t* __restrict__ Bt,
    const float* __restrict__ bias, const float* __restrict__ resid,
    void* __restrict__ Cout, int M, int N, int K, int NTn, int Ksplit, int MTN) {
  __shared__ __align__(16) ushort_t lds[3][2][4096];  // [buf][A|B][8KB] = 48KB
  const int tid = threadIdx.x, lane = tid & 63, wid = tid >> 6;
  const int wm = wid >> 1, wn = wid & 1;
  const int rl = lane & 15, cg = lane >> 4;
  int nwg = gridDim.x;
  int q = nwg >> 3, rr = nwg & 7;
  int xcd = blockIdx.x & 7, idx = blockIdx.x >> 3;
  int wgid = (xcd < rr ? xcd * (q + 1) : rr * (q + 1) + (xcd - rr) * q) + idx;
  const int s = wgid / MTN;
  int rem = wgid - s * MTN;
  const int row0 = (rem / NTn) * 128, col0 = (rem - (rem / NTn) * NTn) * 128;
  const int k0 = s * Ksplit;
  const int NT = Ksplit / 32;

  int soff[2], ldso[2];
  #pragma unroll
  for (int i = 0; i < 2; i++) {
    int ci = wid * 128 + i * 64 + lane;
    int P = ci * 16;
    int L = P ^ (((P >> 7) & 7) << 4);
    int row = L >> 6, kc = (L >> 4) & 3;
    soff[i] = row * K + kc * 8;
    ldso[i] = (wid * 128 + i * 64) * 8;
  }

  f32x4 acc[4][4] = {};

  auto stage = [&](int t, int b) {
    int kk = k0 + t * 32;
    #pragma unroll
    for (int i = 0; i < 2; i++) {
      gload_lds16(A + (size_t)row0 * K + kk + soff[i], &lds[b][0][ldso[i]]);
      gload_lds16(Bt + (size_t)col0 * K + kk + soff[i], &lds[b][1][ldso[i]]);
    }
  };

  auto compute = [&](int b) {
    bf16x8 af[4], bfv[4];
    #pragma unroll
    for (int mi = 0; mi < 4; mi++) {
      int r = wm * 64 + mi * 16 + rl;
      int L = r * 64 + cg * 16;
      int P = L ^ (((L >> 7) & 7) << 4);
      af[mi] = *(const bf16x8*)&lds[b][0][P >> 1];
    }
    #pragma unroll
    for (int ni = 0; ni < 4; ni++) {
      int r = wn * 64 + ni * 16 + rl;
      int L = r * 64 + cg * 16;
      int P = L ^ (((L >> 7) & 7) << 4);
      bfv[ni] = *(const bf16x8*)&lds[b][1][P >> 1];
    }
    __builtin_amdgcn_s_setprio(1);
    #pragma unroll
    for (int mi = 0; mi < 4; mi++)
      #pragma unroll
      for (int ni = 0; ni < 4; ni++)
        acc[mi][ni] = __builtin_amdgcn_mfma_f32_16x16x32_bf16(af[mi], bfv[ni], acc[mi][ni], 0, 0, 0);
    __builtin_amdgcn_s_setprio(0);
  };

  stage(0, 0); stage(1, 1);
  int sb = 2, cb = 0;
  for (int t = 0; t < NT; ++t) {
    if (t < NT - 1) asm volatile("s_waitcnt vmcnt(4)" ::: "memory");
    else            asm volatile("s_waitcnt vmcnt(0)" ::: "memory");
    __builtin_amdgcn_s_barrier();
    __builtin_amdgcn_sched_barrier(0);
    if (t + 2 < NT) { stage(t + 2, sb); sb = (sb == 2) ? 0 : sb + 1; }
    compute(cb);
    cb = (cb == 2) ? 0 : cb + 1;
  }

  if (EPI == 2) {
    float* out = (float*)Cout;
    #pragma unroll
    for (int ni = 0; ni < 4; ni++) {
      int col = col0 + wn * 64 + ni * 16 + rl;
      float bv = bias[col];
      #pragma unroll
      for (int mi = 0; mi < 4; mi++) {
        int rowb = row0 + wm * 64 + mi * 16 + cg * 4;
        #pragma unroll
        for (int j = 0; j < 4; j++)
          out[(size_t)(rowb + j) * N + col] =
              acc[mi][ni][j] + bv + resid[(size_t)(rowb + j) * N + col];
      }
    }
  } else {
    float* out = (float*)Cout + (size_t)s * M * N;
    #pragma unroll
    for (int ni = 0; ni < 4; ni++) {
      int col = col0 + wn * 64 + ni * 16 + rl;
      #pragma unroll
      for (int mi = 0; mi < 4; mi++) {
        int rowb = row0 + wm * 64 + mi * 16 + cg * 4;
        #pragma unroll
        for (int j = 0; j < 4; j++)
          out[(size_t)(rowb + j) * N + col] = acc[mi][ni][j];
      }
    }
  }
}

// ---------------- split-K reduce: out = sum(partials) + bias + resid (fp32, N=1024) ----------------
__global__ __launch_bounds__(256) void reduce_kernel(
    const float* __restrict__ p, const float* __restrict__ bias,
    const float* __restrict__ resid, float* __restrict__ out,
    int S, size_t total4, size_t stride4) {
  const float4* p4 = (const float4*)p;
  const float4* r4 = (const float4*)resid;
  const float4* b4 = (const float4*)bias;
  float4* o4 = (float4*)out;
  for (size_t i = (size_t)blockIdx.x * 256 + threadIdx.x; i < total4;
       i += (size_t)gridDim.x * 256) {
    float4 a = r4[i];
    float4 bb = b4[i & 255];
    a.x += bb.x; a.y += bb.y; a.z += bb.z; a.w += bb.w;
    for (int s = 0; s < S; ++s) {
      float4 v = p4[(size_t)s * stride4 + i];
      a.x += v.x; a.y += v.y; a.z += v.z; a.w += v.w;
    }
    o4[i] = a;
  }
}

// ---------------- flash attention: swapped-QK^T 32x32 MFMA, in-register P ----------------
// Conflict-free LDS chunk swizzle f(R) = (R ^ (R>>3)) & 7 on BOTH sides.
__global__ __launch_bounds__(256) void attn_kernel(
    const ushort_t* __restrict__ qkv, const ushort_t* __restrict__ Vt,
    ushort_t* __restrict__ ctx) {
  __shared__ __align__(16) ushort_t Kl[2][64 * 64];   // [key][d] chunk-XOR, 8KB each
  __shared__ __align__(16) ushort_t Vl[2][64 * 64];   // [d][key] chunk-XOR, 8KB each
  __shared__ float Lt[4][32];
  const int tid = threadIdx.x, lane = tid & 63, wid = tid >> 6;
  int bid = blockIdx.y * 16 + blockIdx.x;
  int w = (bid & 7) * 64 + (bid >> 3);
  const int bh = w >> 4, qt = w & 15;
  const int b = bh >> 4, h = bh & 15;
  const int q0w = qt * 128 + wid * 32;
  const int k31 = lane & 31, sg = lane >> 5;
  const int f0 = (k31 ^ (k31 >> 3)) & 7;           // swizzle for row k31
  const int f1 = (k31 ^ ((k31 >> 3) + 4)) & 7;     // swizzle for row 32+k31
  const ushort_t* Qp = qkv + (size_t)b * SS * 3072 + h * 64;
  const ushort_t* Kp = Qp + 1024;
  const ushort_t* Vg = Vt + (size_t)bh * 64 * SS;

  bf16x8 qf[4];
  {
    const ushort_t* qb = Qp + (size_t)(q0w + k31) * 3072 + sg * 8;
    #pragma unroll
    for (int dsl = 0; dsl < 4; dsl++)
      qf[dsl] = *(const bf16x8*)(qb + dsl * 16);
  }
  float lsum = 0.f;
  f32x16 o0 = {}, o1 = {};

  const int NT = SS / KVBLK;

  int ksrc[2], vsrc[2];
  #pragma unroll
  for (int i = 0; i < 2; i++) {
    int idx = wid * 128 + i * 64 + lane;
    int R = idx >> 3, c = idx & 7;
    int fR = (R ^ (R >> 3)) & 7;
    ksrc[i] = R * 3072 + ((c ^ fR) * 8);
    vsrc[i] = R * SS + ((c ^ fR) * 8);
  }
  const int ldsb = wid * 1024;

  auto stageKV = [&](int buf, int t) {
    size_t kvK = (size_t)t * KVBLK * 3072;
    int kvV = t * KVBLK;
    gload_lds16(Kp + kvK + ksrc[0], &Kl[buf][ldsb]);
    gload_lds16(Kp + kvK + ksrc[1], &Kl[buf][ldsb + 512]);
    gload_lds16(Vg + kvV + vsrc[0], &Vl[buf][ldsb]);
    gload_lds16(Vg + kvV + vsrc[1], &Vl[buf][ldsb + 512]);
  };

  auto softmax_half = [&](const f32x16& s, bf16x8& paE, bf16x8& paO) {
    float pv[16];
    #pragma unroll
    for (int r = 0; r < 16; r++) pv[r] = __builtin_amdgcn_exp2f(s[r]);
    #pragma unroll
    for (int r = 0; r < 16; r++) lsum += pv[r];
    unsigned W[4][2];
    #pragma unroll
    for (int qd = 0; qd < 4; qd++) {
      asm("v_cvt_pk_bf16_f32 %0, %1, %2" : "=v"(W[qd][0]) : "v"(pv[4 * qd]), "v"(pv[4 * qd + 1]));
      asm("v_cvt_pk_bf16_f32 %0, %1, %2" : "=v"(W[qd][1]) : "v"(pv[4 * qd + 2]), "v"(pv[4 * qd + 3]));
    }
    unsigned a0 = W[1][0], b0 = W[0][0], a1 = W[1][1], b1 = W[0][1];
    asm("v_permlane32_swap_b32 %0, %1" : "+v"(a0), "+v"(b0));
    asm("v_permlane32_swap_b32 %0, %1" : "+v"(a1), "+v"(b1));
    paE = pack4w(b0, b1, a0, a1);
    unsigned a2 = W[3][0], b2 = W[2][0], a3 = W[3][1], b3 = W[2][1];
    asm("v_permlane32_swap_b32 %0, %1" : "+v"(a2), "+v"(b2));
    asm("v_permlane32_swap_b32 %0, %1" : "+v"(a3), "+v"(b3));
    paO = pack4w(b2, b3, a2, a3);
  };

  auto body = [&](int t, int cb) {
    __syncthreads();
    if (t + 1 < NT) stageKV(cb ^ 1, t + 1);

    f32x16 s0 = {}, s1 = {};
    #pragma unroll
    for (int dsl = 0; dsl < 4; dsl++) {
      int chl = dsl * 2 + sg;
      bf16x8 kf0 = *(const bf16x8*)(&Kl[cb][k31 * 64 + ((chl ^ f0) * 8)]);
      bf16x8 kf1 = *(const bf16x8*)(&Kl[cb][(32 + k31) * 64 + ((chl ^ f1) * 8)]);
      s0 = __builtin_amdgcn_mfma_f32_32x32x16_bf16(kf0, qf[dsl], s0, 0, 0, 0);
      s1 = __builtin_amdgcn_mfma_f32_32x32x16_bf16(kf1, qf[dsl], s1, 0, 0, 0);
    }
    bf16x8 pa[4];
    softmax_half(s0, pa[0], pa[1]);
    softmax_half(s1, pa[2], pa[3]);
    #pragma unroll
    for (int ks = 0; ks < 4; ks++) {
      int chl = 2 * ks + sg;
      bf16x8 vf0 = *(const bf16x8*)(&Vl[cb][k31 * 64 + ((chl ^ f0) * 8)]);
      bf16x8 vf1 = *(const bf16x8*)(&Vl[cb][(32 + k31) * 64 + ((chl ^ f1) * 8)]);
      o0 = __builtin_amdgcn_mfma_f32_32x32x16_bf16(pa[ks], vf0, o0, 0, 0, 0);
      o1 = __builtin_amdgcn_mfma_f32_32x32x16_bf16(pa[ks], vf1, o1, 0, 0, 0);
    }
  };

  stageKV(0, 0);
  for (int t = 0; t < NT; t += 2) {
    body(t, 0);
    body(t + 1, 1);
  }

  float ltot = lsum + __shfl_xor(lsum, 32);
  if (lane < 32) Lt[wid][lane] = ltot;
  asm volatile("s_waitcnt lgkmcnt(0)" ::: "memory");
  __builtin_amdgcn_sched_barrier(0);

  const int colb = h * 64 + k31;
  #pragma unroll
  for (int r = 0; r < 16; r++) {
    int qp = (r & 3) + 8 * (r >> 2) + 4 * sg;
    float rlq = 1.0f / Lt[wid][qp];
    size_t row = (size_t)(b * SS + q0w + qp);
    ctx[row * D_MODEL + colb] = f2bf(o0[r] * rlq);
    ctx[row * D_MODEL + colb + 32] = f2bf(o1[r] * rlq);
  }
}

extern "C" void kernel_launch(void* const* d_in, const int* in_sizes, int n_in,
                              void* d_out, int out_size, void* d_ws, size_t ws_size,
                              hipStream_t stream) {
  const float* x    = (const float*)d_in[0];
  const float* ln1w = (const float*)d_in[1];
  const float* ln1b = (const float*)d_in[2];
  const float* Wq   = (const float*)d_in[3];
  const float* bq   = (const float*)d_in[4];
  const float* Wk   = (const float*)d_in[5];
  const float* bk   = (const float*)d_in[6];
  const float* Wv   = (const float*)d_in[7];
  const float* bv   = (const float*)d_in[8];
  const float* Wo   = (const float*)d_in[9];
  const float* bo   = (const float*)d_in[10];
  const float* ln2w = (const float*)d_in[11];
  const float* ln2b = (const float*)d_in[12];
  const float* W1   = (const float*)d_in[13];
  const float* b1   = (const float*)d_in[14];
  const float* W2   = (const float*)d_in[15];
  const float* b2   = (const float*)d_in[16];

  char* ws = (char*)d_ws;
  size_t off = 0;
  auto alloc = [&](size_t bytes) {
    void* p = ws + off;
    off += (bytes + 255) & ~(size_t)255;
    return p;
  };
  ushort_t* Wt_qkv = (ushort_t*)alloc((size_t)3072 * 1024 * 2);
  ushort_t* Wt_o   = (ushort_t*)alloc((size_t)1024 * 1024 * 2);
  ushort_t* Wt_1   = (ushort_t*)alloc((size_t)4096 * 1024 * 2);
  ushort_t* Wt_2   = (ushort_t*)alloc((size_t)1024 * 4096 * 2);
  float*    bqkv   = (float*)alloc((size_t)3072 * 4);
  ushort_t* qkvb   = (ushort_t*)alloc((size_t)MROWS * 3072 * 2);  // 24 MB
  ushort_t* ctxb   = (ushort_t*)alloc((size_t)MROWS * 1024 * 2);  // 8 MB
  ushort_t* hbuf   = (ushort_t*)alloc((size_t)MROWS * 1024 * 2);
  float*    x2     = (float*)alloc((size_t)MROWS * 1024 * 4);
  ushort_t* Vtb    = (ushort_t*)alloc((size_t)BB * NH * 64 * SS * 2);  // 8 MB
  ushort_t* ff1    = qkvb;  // reuse qkv(24MB)+ctx(8MB) = 32MB for [4096][4096] bf16
  float*    outp   = (float*)d_out;

  // split-K=2 partials for FFN2 (32 MB); fallback to fused if no room
  const size_t partial1 = (size_t)MROWS * 1024 * 4;  // 16 MB per split
  int S = (ws_size - off >= 2 * partial1 + 256) ? 2 : 1;
  float* pbuf = (S == 2) ? (float*)alloc(2 * partial1) : nullptr;

  // unified prep: all weight transposes + bias pack in one launch
  prep_kernel<<<dim3(12300), dim3(32, 8), 0, stream>>>(
      Wq, Wk, Wv, Wo, W1, W2, bq, bk, bv, Wt_qkv, Wt_o, Wt_1, Wt_2, bqkv);

  // LN1 -> h
  ln_bf16_kernel<<<MROWS, 256, 0, stream>>>(x, ln1w, ln1b, hbuf);
  // fused QKV GEMM: Q/K -> qkvb (Q pre-scaled by Cs); V col-tiles written transposed to Vtb
  gemm256w_kernel<0><<<dim3(32 * 12), 256, 0, stream>>>(
      hbuf, Wt_qkv, bqkv, qkvb, Vtb, MROWS, 3072, 1024, 12);
  // attention: 128 q/block, 512 blocks
  attn_kernel<<<dim3(SS / 128, BB * NH), 256, 0, stream>>>(qkvb, Vtb, ctxb);
  // O-proj + bias + residual(x) -> x2 (fp32), fused
  gemm128_kernel<2><<<dim3(8 * 32), 256, 0, stream>>>(
      ctxb, Wt_o, bo, x, x2, MROWS, 1024, 1024, 8, 1024, 8 * 32);
  // LN2 -> h
  ln_bf16_kernel<<<MROWS, 256, 0, stream>>>(x2, ln2w, ln2b, hbuf);
  // FFN1 + relu -> ff1 (bf16); 128x256 tiles, 512 blocks = exact 2/CU
  gemm256w_kernel<1><<<dim3(32 * 16), 256, 0, stream>>>(
      hbuf, Wt_1, b1, ff1, nullptr, MROWS, D_FF, 1024, 16);
  // FFN2: split-K=2 -> fp32 partials; reduce adds bias b2 + resid x2 -> out
  if (S == 2) {
    gemm128_kernel<3><<<dim3(8 * 32 * 2), 256, 0, stream>>>(
        ff1, Wt_2, nullptr, nullptr, pbuf, MROWS, 1024, 4096, 8, 2048, 8 * 32);
    reduce_kernel<<<2048, 256, 0, stream>>>(pbuf, b2, x2, outp, 2,
        (size_t)MROWS * 1024 / 4, (size_t)MROWS * 1024 / 4);
  } else {
    gemm128_kernel<2><<<dim3(8 * 32), 256, 0, stream>>>(
        ff1, Wt_2, b2, x2, outp, MROWS, 1024, 4096, 8, 4096, 8 * 32);
  }
}

// Round 21
// 221.350 us; speedup vs baseline: 1.0906x; 1.0015x over previous
//
#include <hip/hip_runtime.h>
#include <hip/hip_bf16.h>
#include <cstdint>
#include <cstddef>

typedef unsigned short ushort_t;
typedef __bf16 bf16x8 __attribute__((ext_vector_type(8)));
typedef float f32x4 __attribute__((ext_vector_type(4)));
typedef float f32x16 __attribute__((ext_vector_type(16)));

#define D_MODEL 1024
#define D_FF 4096
#define BB 2
#define SS 2048
#define NH 16
#define MROWS (BB * SS) /* 4096 */
#define KVBLK 64

__device__ __forceinline__ ushort_t f2bf(float f) {
  union { float f; unsigned u; } x; x.f = f;
  unsigned r = x.u + 0x7fffu + ((x.u >> 16) & 1u);
  return (ushort_t)(r >> 16);
}

__device__ __forceinline__ void gload_lds16(const void* g, void* l) {
  __builtin_amdgcn_global_load_lds((const __attribute__((address_space(1))) void*)g,
                                   (__attribute__((address_space(3))) void*)l, 16, 0, 0);
}

__device__ __forceinline__ bf16x8 pack4w(unsigned w0, unsigned w1, unsigned w2, unsigned w3) {
  union { unsigned u[4]; bf16x8 v; } t;
  t.u[0] = w0; t.u[1] = w1; t.u[2] = w2; t.u[3] = w3;
  return t.v;
}

// ---------------- LayerNorm (fp32 in -> bf16 out) ----------------
__global__ __launch_bounds__(256) void ln_bf16_kernel(
    const float* __restrict__ x, const float* __restrict__ w,
    const float* __restrict__ b, ushort_t* __restrict__ out) {
  int row = blockIdx.x;
  int tid = threadIdx.x;
  int lane = tid & 63, wid = tid >> 6;
  const float4 v = ((const float4*)(x + (size_t)row * D_MODEL))[tid];
  float s = v.x + v.y + v.z + v.w;
  __shared__ float red[8];
  #pragma unroll
  for (int o = 32; o > 0; o >>= 1) s += __shfl_down(s, o);
  if (lane == 0) red[wid] = s;
  __syncthreads();
  float mu = (red[0] + red[1] + red[2] + red[3]) * (1.0f / D_MODEL);
  float d0 = v.x - mu, d1 = v.y - mu, d2 = v.z - mu, d3 = v.w - mu;
  float sq = d0 * d0 + d1 * d1 + d2 * d2 + d3 * d3;
  #pragma unroll
  for (int o = 32; o > 0; o >>= 1) sq += __shfl_down(sq, o);
  if (lane == 0) red[4 + wid] = sq;
  __syncthreads();
  float var = (red[4] + red[5] + red[6] + red[7]) * (1.0f / D_MODEL);
  float rstd = rsqrtf(var + 1e-5f);
  const float4 wv = ((const float4*)w)[tid];
  const float4 bv = ((const float4*)b)[tid];
  ushort4 o4;
  o4.x = f2bf(d0 * rstd * wv.x + bv.x);
  o4.y = f2bf(d1 * rstd * wv.y + bv.y);
  o4.z = f2bf(d2 * rstd * wv.z + bv.z);
  o4.w = f2bf(d3 * rstd * wv.w + bv.w);
  ((ushort4*)(out + (size_t)row * D_MODEL))[tid] = o4;
}

// ---------------- unified prep: 6 transposes + bias pack + LN1 (all independent) ----------------
// blocks 0..12287: weight transposes; 12288..12299: bias pack; 12300..16395: LN1 rows.
__global__ __launch_bounds__(256) void prep_kernel(
    const float* __restrict__ Wq, const float* __restrict__ Wk,
    const float* __restrict__ Wv, const float* __restrict__ Wo,
    const float* __restrict__ W1, const float* __restrict__ W2,
    const float* __restrict__ bq, const float* __restrict__ bk,
    const float* __restrict__ bv,
    ushort_t* __restrict__ Dqkv, ushort_t* __restrict__ Do_,
    ushort_t* __restrict__ D1, ushort_t* __restrict__ D2,
    float* __restrict__ bqkv,
    const float* __restrict__ x, const float* __restrict__ ln1w,
    const float* __restrict__ ln1b, ushort_t* __restrict__ hbuf) {
  const int id = blockIdx.x;
  const int tx = threadIdx.x, ty = threadIdx.y;  // 32 x 8
  const int tid = ty * 32 + tx;
  if (id >= 12300) {
    // LN1 for row (id - 12300)
    int row = id - 12300;
    int lane = tid & 63, wid = tid >> 6;
    const float4 v = ((const float4*)(x + (size_t)row * D_MODEL))[tid];
    float s = v.x + v.y + v.z + v.w;
    __shared__ float red[8];
    #pragma unroll
    for (int o = 32; o > 0; o >>= 1) s += __shfl_down(s, o);
    if (lane == 0) red[wid] = s;
    __syncthreads();
    float mu = (red[0] + red[1] + red[2] + red[3]) * (1.0f / D_MODEL);
    float d0 = v.x - mu, d1 = v.y - mu, d2 = v.z - mu, d3 = v.w - mu;
    float sq = d0 * d0 + d1 * d1 + d2 * d2 + d3 * d3;
    #pragma unroll
    for (int o = 32; o > 0; o >>= 1) sq += __shfl_down(sq, o);
    if (lane == 0) red[4 + wid] = sq;
    __syncthreads();
    float var = (red[4] + red[5] + red[6] + red[7]) * (1.0f / D_MODEL);
    float rstd = rsqrtf(var + 1e-5f);
    const float4 wv = ((const float4*)ln1w)[tid];
    const float4 bv = ((const float4*)ln1b)[tid];
    ushort4 o4;
    o4.x = f2bf(d0 * rstd * wv.x + bv.x);
    o4.y = f2bf(d1 * rstd * wv.y + bv.y);
    o4.z = f2bf(d2 * rstd * wv.z + bv.z);
    o4.w = f2bf(d3 * rstd * wv.w + bv.w);
    ((ushort4*)(hbuf + (size_t)row * D_MODEL))[tid] = o4;
    return;
  }
  if (id >= 12288) {
    int i = (id - 12288) * 256 + tid;
    float v = (i < 1024) ? bq[i] : (i < 2048) ? bk[i - 1024] : bv[i - 2048];
    bqkv[i] = v;
    return;
  }
  __shared__ float tile[32][33];
  const float* W;
  ushort_t* Wt;
  int K, N, bx, by;
  if (id < 4096) {
    int z = id >> 10, t = id & 1023;
    W = (z == 0) ? Wq : (z == 1) ? Wk : (z == 2) ? Wv : Wo;
    Wt = (z < 3) ? (Dqkv + (size_t)z * 1024 * 1024) : Do_;
    K = 1024; N = 1024; bx = (t & 31) * 32; by = (t >> 5) * 32;
  } else if (id < 8192) {
    int t = id - 4096;
    W = W1; Wt = D1; K = 1024; N = 4096;
    bx = (t & 127) * 32; by = (t >> 7) * 32;
  } else {
    int t = id - 8192;
    W = W2; Wt = D2; K = 4096; N = 1024;
    bx = (t & 31) * 32; by = (t >> 5) * 32;
  }
  #pragma unroll
  for (int i = 0; i < 32; i += 8)
    tile[ty + i][tx] = W[(size_t)(by + ty + i) * N + bx + tx];
  __syncthreads();
  #pragma unroll
  for (int i = 0; i < 32; i += 8)
    Wt[(size_t)(bx + ty + i) * K + by + tx] = f2bf(tile[tx][ty + i]);
}

// ---------------- GEMM 128x256, BK=32, 3-buffer LDS ring (72KB -> 2 blocks/CU) ----------------
// EPI: 0 = QKV: bf16 + bias, Q cols scaled by Cs; V col-tiles (col0>=2048) written
//      TRANSPOSED directly to Vt[bh][64][2048]; 1 = bf16 + bias + relu.
template <int EPI>
__global__ __launch_bounds__(256, 2) void gemm256w_kernel(
    const ushort_t* __restrict__ A, const ushort_t* __restrict__ Bt,
    const float* __restrict__ bias, void* __restrict__ Cout,
    ushort_t* __restrict__ Vt, int M, int N, int K, int NTn) {
  __shared__ __align__(16) ushort_t ldsA[3][4096];  // 8KB each
  __shared__ __align__(16) ushort_t ldsB[3][8192];  // 16KB each
  const int tid = threadIdx.x, lane = tid & 63, wid = tid >> 6;
  const int wm = wid >> 1, wn = wid & 1;
  const int rl = lane & 15, cg = lane >> 4;
  int nwg = gridDim.x;
  int q = nwg >> 3, rr = nwg & 7;
  int xcd = blockIdx.x & 7, idx = blockIdx.x >> 3;
  int wgid = (xcd < rr ? xcd * (q + 1) : rr * (q + 1) + (xcd - rr) * q) + idx;
  const int row0 = (wgid / NTn) * 128, col0 = (wgid - (wgid / NTn) * NTn) * 256;
  const int NT = K / 32;

  int soffA[2], ldsoA[2], soffB[4], ldsoB[4];
  #pragma unroll
  for (int i = 0; i < 2; i++) {
    int ci = wid * 128 + i * 64 + lane;
    int P = ci * 16;
    int L = P ^ (((P >> 7) & 7) << 4);
    soffA[i] = (L >> 6) * K + ((L >> 4) & 3) * 8;
    ldsoA[i] = (wid * 128 + i * 64) * 8;
  }
  #pragma unroll
  for (int i = 0; i < 4; i++) {
    int ci = wid * 256 + i * 64 + lane;
    int P = ci * 16;
    int L = P ^ (((P >> 7) & 7) << 4);
    soffB[i] = (L >> 6) * K + ((L >> 4) & 3) * 8;
    ldsoB[i] = (wid * 256 + i * 64) * 8;
  }

  f32x4 acc[4][8] = {};

  auto stage = [&](int t, int b) {
    int kk = t * 32;
    #pragma unroll
    for (int i = 0; i < 2; i++)
      gload_lds16(A + (size_t)row0 * K + kk + soffA[i], &ldsA[b][ldsoA[i]]);
    #pragma unroll
    for (int i = 0; i < 4; i++)
      gload_lds16(Bt + (size_t)col0 * K + kk + soffB[i], &ldsB[b][ldsoB[i]]);
  };

  auto compute = [&](int b) {
    bf16x8 af[4], bfv[8];
    #pragma unroll
    for (int mi = 0; mi < 4; mi++) {
      int r = wm * 64 + mi * 16 + rl;
      int L = r * 64 + cg * 16;
      int P = L ^ (((L >> 7) & 7) << 4);
      af[mi] = *(const bf16x8*)&ldsA[b][P >> 1];
    }
    #pragma unroll
    for (int ni = 0; ni < 8; ni++) {
      int r = wn * 128 + ni * 16 + rl;
      int L = r * 64 + cg * 16;
      int P = L ^ (((L >> 7) & 7) << 4);
      bfv[ni] = *(const bf16x8*)&ldsB[b][P >> 1];
    }
    __builtin_amdgcn_s_setprio(1);
    #pragma unroll
    for (int mi = 0; mi < 4; mi++)
      #pragma unroll
      for (int ni = 0; ni < 8; ni++)
        acc[mi][ni] = __builtin_amdgcn_mfma_f32_16x16x32_bf16(af[mi], bfv[ni], acc[mi][ni], 0, 0, 0);
    __builtin_amdgcn_s_setprio(0);
  };

  stage(0, 0); stage(1, 1);
  int sb = 2, cb = 0;
  for (int t = 0; t < NT; ++t) {
    if (t < NT - 1) asm volatile("s_waitcnt vmcnt(6)" ::: "memory");
    else            asm volatile("s_waitcnt vmcnt(0)" ::: "memory");
    __builtin_amdgcn_s_barrier();
    __builtin_amdgcn_sched_barrier(0);
    if (t + 2 < NT) { stage(t + 2, sb); sb = (sb == 2) ? 0 : sb + 1; }
    compute(cb);
    cb = (cb == 2) ? 0 : cb + 1;
  }

  if (EPI == 0 && col0 >= 2048) {
    const int bb = row0 >> 11;
    const int keyb = (row0 & 2047) + wm * 64;
    #pragma unroll
    for (int ni = 0; ni < 8; ni++) {
      int col = col0 + wn * 128 + ni * 16 + rl;
      float bv = bias[col];
      int vcol = col - 2048;
      ushort_t* drow = Vt + ((size_t)(bb * 16 + (vcol >> 6)) * 64 + (vcol & 63)) * SS;
      #pragma unroll
      for (int mi = 0; mi < 4; mi++) {
        int key0 = keyb + mi * 16 + cg * 4;
        ushort4 pk;
        pk.x = f2bf(acc[mi][ni][0] + bv);
        pk.y = f2bf(acc[mi][ni][1] + bv);
        pk.z = f2bf(acc[mi][ni][2] + bv);
        pk.w = f2bf(acc[mi][ni][3] + bv);
        *(ushort4*)(drow + key0) = pk;
      }
    }
  } else {
    ushort_t* out = (ushort_t*)Cout;
    #pragma unroll
    for (int ni = 0; ni < 8; ni++) {
      int col = col0 + wn * 128 + ni * 16 + rl;
      float bv = bias[col];
      float sc = (EPI == 0 && col < 1024) ? 0.18033688011f : 1.0f;
      #pragma unroll
      for (int mi = 0; mi < 4; mi++) {
        int rowb = row0 + wm * 64 + mi * 16 + cg * 4;
        #pragma unroll
        for (int j = 0; j < 4; j++) {
          float v = acc[mi][ni][j] + bv;
          if (EPI == 1) v = fmaxf(v, 0.0f);
          if (EPI == 0) v *= sc;
          out[(size_t)(rowb + j) * N + col] = f2bf(v);
        }
      }
    }
  }
}

// ---------------- GEMM 128x128, BK=32, 3-buffer LDS ring (48KB -> 3 blocks/CU) ----------------
// EPI: 2 = fp32 + bias + resid (fused); 3 = fp32 partial at Cout + s*M*N (split-K).
template <int EPI>
__global__ __launch_bounds__(256, 3) void gemm128_kernel(
    const ushort_t* __restrict__ A, const ushort_t* __restrict__ Bt,
    const float* __restrict__ bias, const float* __restrict__ resid,
    void* __restrict__ Cout, int M, int N, int K, int NTn, int Ksplit, int MTN) {
  __shared__ __align__(16) ushort_t lds[3][2][4096];  // [buf][A|B][8KB] = 48KB
  const int tid = threadIdx.x, lane = tid & 63, wid = tid >> 6;
  const int wm = wid >> 1, wn = wid & 1;
  const int rl = lane & 15, cg = lane >> 4;
  int nwg = gridDim.x;
  int q = nwg >> 3, rr = nwg & 7;
  int xcd = blockIdx.x & 7, idx = blockIdx.x >> 3;
  int wgid = (xcd < rr ? xcd * (q + 1) : rr * (q + 1) + (xcd - rr) * q) + idx;
  const int s = wgid / MTN;
  int rem = wgid - s * MTN;
  const int row0 = (rem / NTn) * 128, col0 = (rem - (rem / NTn) * NTn) * 128;
  const int k0 = s * Ksplit;
  const int NT = Ksplit / 32;

  int soff[2], ldso[2];
  #pragma unroll
  for (int i = 0; i < 2; i++) {
    int ci = wid * 128 + i * 64 + lane;
    int P = ci * 16;
    int L = P ^ (((P >> 7) & 7) << 4);
    int row = L >> 6, kc = (L >> 4) & 3;
    soff[i] = row * K + kc * 8;
    ldso[i] = (wid * 128 + i * 64) * 8;
  }

  f32x4 acc[4][4] = {};

  auto stage = [&](int t, int b) {
    int kk = k0 + t * 32;
    #pragma unroll
    for (int i = 0; i < 2; i++) {
      gload_lds16(A + (size_t)row0 * K + kk + soff[i], &lds[b][0][ldso[i]]);
      gload_lds16(Bt + (size_t)col0 * K + kk + soff[i], &lds[b][1][ldso[i]]);
    }
  };

  auto compute = [&](int b) {
    bf16x8 af[4], bfv[4];
    #pragma unroll
    for (int mi = 0; mi < 4; mi++) {
      int r = wm * 64 + mi * 16 + rl;
      int L = r * 64 + cg * 16;
      int P = L ^ (((L >> 7) & 7) << 4);
      af[mi] = *(const bf16x8*)&lds[b][0][P >> 1];
    }
    #pragma unroll
    for (int ni = 0; ni < 4; ni++) {
      int r = wn * 64 + ni * 16 + rl;
      int L = r * 64 + cg * 16;
      int P = L ^ (((L >> 7) & 7) << 4);
      bfv[ni] = *(const bf16x8*)&lds[b][1][P >> 1];
    }
    __builtin_amdgcn_s_setprio(1);
    #pragma unroll
    for (int mi = 0; mi < 4; mi++)
      #pragma unroll
      for (int ni = 0; ni < 4; ni++)
        acc[mi][ni] = __builtin_amdgcn_mfma_f32_16x16x32_bf16(af[mi], bfv[ni], acc[mi][ni], 0, 0, 0);
    __builtin_amdgcn_s_setprio(0);
  };

  stage(0, 0); stage(1, 1);
  int sb = 2, cb = 0;
  for (int t = 0; t < NT; ++t) {
    if (t < NT - 1) asm volatile("s_waitcnt vmcnt(4)" ::: "memory");
    else            asm volatile("s_waitcnt vmcnt(0)" ::: "memory");
    __builtin_amdgcn_s_barrier();
    __builtin_amdgcn_sched_barrier(0);
    if (t + 2 < NT) { stage(t + 2, sb); sb = (sb == 2) ? 0 : sb + 1; }
    compute(cb);
    cb = (cb == 2) ? 0 : cb + 1;
  }

  if (EPI == 2) {
    float* out = (float*)Cout;
    #pragma unroll
    for (int ni = 0; ni < 4; ni++) {
      int col = col0 + wn * 64 + ni * 16 + rl;
      float bv = bias[col];
      #pragma unroll
      for (int mi = 0; mi < 4; mi++) {
        int rowb = row0 + wm * 64 + mi * 16 + cg * 4;
        #pragma unroll
        for (int j = 0; j < 4; j++)
          out[(size_t)(rowb + j) * N + col] =
              acc[mi][ni][j] + bv + resid[(size_t)(rowb + j) * N + col];
      }
    }
  } else {
    float* out = (float*)Cout + (size_t)s * M * N;
    #pragma unroll
    for (int ni = 0; ni < 4; ni++) {
      int col = col0 + wn * 64 + ni * 16 + rl;
      #pragma unroll
      for (int mi = 0; mi < 4; mi++) {
        int rowb = row0 + wm * 64 + mi * 16 + cg * 4;
        #pragma unroll
        for (int j = 0; j < 4; j++)
          out[(size_t)(rowb + j) * N + col] = acc[mi][ni][j];
      }
    }
  }
}

// ---------------- split-K reduce: out = sum(partials) + bias + resid (fp32, N=1024) ----------------
__global__ __launch_bounds__(256) void reduce_kernel(
    const float* __restrict__ p, const float* __restrict__ bias,
    const float* __restrict__ resid, float* __restrict__ out,
    int S, size_t total4, size_t stride4) {
  const float4* p4 = (const float4*)p;
  const float4* r4 = (const float4*)resid;
  const float4* b4 = (const float4*)bias;
  float4* o4 = (float4*)out;
  for (size_t i = (size_t)blockIdx.x * 256 + threadIdx.x; i < total4;
       i += (size_t)gridDim.x * 256) {
    float4 a = r4[i];
    float4 bb = b4[i & 255];
    a.x += bb.x; a.y += bb.y; a.z += bb.z; a.w += bb.w;
    for (int s = 0; s < S; ++s) {
      float4 v = p4[(size_t)s * stride4 + i];
      a.x += v.x; a.y += v.y; a.z += v.z; a.w += v.w;
    }
    o4[i] = a;
  }
}

// ---------------- flash attention: swapped-QK^T 32x32 MFMA, in-register P ----------------
// Conflict-free LDS chunk swizzle f(R) = (R ^ (R>>3)) & 7 on BOTH sides.
__global__ __launch_bounds__(256) void attn_kernel(
    const ushort_t* __restrict__ qkv, const ushort_t* __restrict__ Vt,
    ushort_t* __restrict__ ctx) {
  __shared__ __align__(16) ushort_t Kl[2][64 * 64];   // [key][d] chunk-XOR, 8KB each
  __shared__ __align__(16) ushort_t Vl[2][64 * 64];   // [d][key] chunk-XOR, 8KB each
  __shared__ float Lt[4][32];
  const int tid = threadIdx.x, lane = tid & 63, wid = tid >> 6;
  int bid = blockIdx.y * 16 + blockIdx.x;
  int w = (bid & 7) * 64 + (bid >> 3);
  const int bh = w >> 4, qt = w & 15;
  const int b = bh >> 4, h = bh & 15;
  const int q0w = qt * 128 + wid * 32;
  const int k31 = lane & 31, sg = lane >> 5;
  const int f0 = (k31 ^ (k31 >> 3)) & 7;           // swizzle for row k31
  const int f1 = (k31 ^ ((k31 >> 3) + 4)) & 7;     // swizzle for row 32+k31
  const ushort_t* Qp = qkv + (size_t)b * SS * 3072 + h * 64;
  const ushort_t* Kp = Qp + 1024;
  const ushort_t* Vg = Vt + (size_t)bh * 64 * SS;

  bf16x8 qf[4];
  {
    const ushort_t* qb = Qp + (size_t)(q0w + k31) * 3072 + sg * 8;
    #pragma unroll
    for (int dsl = 0; dsl < 4; dsl++)
      qf[dsl] = *(const bf16x8*)(qb + dsl * 16);
  }
  float lsum = 0.f;
  f32x16 o0 = {}, o1 = {};

  const int NT = SS / KVBLK;

  int ksrc[2], vsrc[2];
  #pragma unroll
  for (int i = 0; i < 2; i++) {
    int idx = wid * 128 + i * 64 + lane;
    int R = idx >> 3, c = idx & 7;
    int fR = (R ^ (R >> 3)) & 7;
    ksrc[i] = R * 3072 + ((c ^ fR) * 8);
    vsrc[i] = R * SS + ((c ^ fR) * 8);
  }
  const int ldsb = wid * 1024;

  auto stageKV = [&](int buf, int t) {
    size_t kvK = (size_t)t * KVBLK * 3072;
    int kvV = t * KVBLK;
    gload_lds16(Kp + kvK + ksrc[0], &Kl[buf][ldsb]);
    gload_lds16(Kp + kvK + ksrc[1], &Kl[buf][ldsb + 512]);
    gload_lds16(Vg + kvV + vsrc[0], &Vl[buf][ldsb]);
    gload_lds16(Vg + kvV + vsrc[1], &Vl[buf][ldsb + 512]);
  };

  auto softmax_half = [&](const f32x16& s, bf16x8& paE, bf16x8& paO) {
    float pv[16];
    #pragma unroll
    for (int r = 0; r < 16; r++) pv[r] = __builtin_amdgcn_exp2f(s[r]);
    #pragma unroll
    for (int r = 0; r < 16; r++) lsum += pv[r];
    unsigned W[4][2];
    #pragma unroll
    for (int qd = 0; qd < 4; qd++) {
      asm("v_cvt_pk_bf16_f32 %0, %1, %2" : "=v"(W[qd][0]) : "v"(pv[4 * qd]), "v"(pv[4 * qd + 1]));
      asm("v_cvt_pk_bf16_f32 %0, %1, %2" : "=v"(W[qd][1]) : "v"(pv[4 * qd + 2]), "v"(pv[4 * qd + 3]));
    }
    unsigned a0 = W[1][0], b0 = W[0][0], a1 = W[1][1], b1 = W[0][1];
    asm("v_permlane32_swap_b32 %0, %1" : "+v"(a0), "+v"(b0));
    asm("v_permlane32_swap_b32 %0, %1" : "+v"(a1), "+v"(b1));
    paE = pack4w(b0, b1, a0, a1);
    unsigned a2 = W[3][0], b2 = W[2][0], a3 = W[3][1], b3 = W[2][1];
    asm("v_permlane32_swap_b32 %0, %1" : "+v"(a2), "+v"(b2));
    asm("v_permlane32_swap_b32 %0, %1" : "+v"(a3), "+v"(b3));
    paO = pack4w(b2, b3, a2, a3);
  };

  auto body = [&](int t, int cb) {
    __syncthreads();
    if (t + 1 < NT) stageKV(cb ^ 1, t + 1);

    f32x16 s0 = {}, s1 = {};
    #pragma unroll
    for (int dsl = 0; dsl < 4; dsl++) {
      int chl = dsl * 2 + sg;
      bf16x8 kf0 = *(const bf16x8*)(&Kl[cb][k31 * 64 + ((chl ^ f0) * 8)]);
      bf16x8 kf1 = *(const bf16x8*)(&Kl[cb][(32 + k31) * 64 + ((chl ^ f1) * 8)]);
      s0 = __builtin_amdgcn_mfma_f32_32x32x16_bf16(kf0, qf[dsl], s0, 0, 0, 0);
      s1 = __builtin_amdgcn_mfma_f32_32x32x16_bf16(kf1, qf[dsl], s1, 0, 0, 0);
    }
    bf16x8 pa[4];
    softmax_half(s0, pa[0], pa[1]);
    softmax_half(s1, pa[2], pa[3]);
    #pragma unroll
    for (int ks = 0; ks < 4; ks++) {
      int chl = 2 * ks + sg;
      bf16x8 vf0 = *(const bf16x8*)(&Vl[cb][k31 * 64 + ((chl ^ f0) * 8)]);
      bf16x8 vf1 = *(const bf16x8*)(&Vl[cb][(32 + k31) * 64 + ((chl ^ f1) * 8)]);
      o0 = __builtin_amdgcn_mfma_f32_32x32x16_bf16(pa[ks], vf0, o0, 0, 0, 0);
      o1 = __builtin_amdgcn_mfma_f32_32x32x16_bf16(pa[ks], vf1, o1, 0, 0, 0);
    }
  };

  stageKV(0, 0);
  for (int t = 0; t < NT; t += 2) {
    body(t, 0);
    body(t + 1, 1);
  }

  float ltot = lsum + __shfl_xor(lsum, 32);
  if (lane < 32) Lt[wid][lane] = ltot;
  asm volatile("s_waitcnt lgkmcnt(0)" ::: "memory");
  __builtin_amdgcn_sched_barrier(0);

  const int colb = h * 64 + k31;
  #pragma unroll
  for (int r = 0; r < 16; r++) {
    int qp = (r & 3) + 8 * (r >> 2) + 4 * sg;
    float rlq = 1.0f / Lt[wid][qp];
    size_t row = (size_t)(b * SS + q0w + qp);
    ctx[row * D_MODEL + colb] = f2bf(o0[r] * rlq);
    ctx[row * D_MODEL + colb + 32] = f2bf(o1[r] * rlq);
  }
}

extern "C" void kernel_launch(void* const* d_in, const int* in_sizes, int n_in,
                              void* d_out, int out_size, void* d_ws, size_t ws_size,
                              hipStream_t stream) {
  const float* x    = (const float*)d_in[0];
  const float* ln1w = (const float*)d_in[1];
  const float* ln1b = (const float*)d_in[2];
  const float* Wq   = (const float*)d_in[3];
  const float* bq   = (const float*)d_in[4];
  const float* Wk   = (const float*)d_in[5];
  const float* bk   = (const float*)d_in[6];
  const float* Wv   = (const float*)d_in[7];
  const float* bv   = (const float*)d_in[8];
  const float* Wo   = (const float*)d_in[9];
  const float* bo   = (const float*)d_in[10];
  const float* ln2w = (const float*)d_in[11];
  const float* ln2b = (const float*)d_in[12];
  const float* W1   = (const float*)d_in[13];
  const float* b1   = (const float*)d_in[14];
  const float* W2   = (const float*)d_in[15];
  const float* b2   = (const float*)d_in[16];

  char* ws = (char*)d_ws;
  size_t off = 0;
  auto alloc = [&](size_t bytes) {
    void* p = ws + off;
    off += (bytes + 255) & ~(size_t)255;
    return p;
  };
  ushort_t* Wt_qkv = (ushort_t*)alloc((size_t)3072 * 1024 * 2);
  ushort_t* Wt_o   = (ushort_t*)alloc((size_t)1024 * 1024 * 2);
  ushort_t* Wt_1   = (ushort_t*)alloc((size_t)4096 * 1024 * 2);
  ushort_t* Wt_2   = (ushort_t*)alloc((size_t)1024 * 4096 * 2);
  float*    bqkv   = (float*)alloc((size_t)3072 * 4);
  ushort_t* qkvb   = (ushort_t*)alloc((size_t)MROWS * 3072 * 2);  // 24 MB
  ushort_t* ctxb   = (ushort_t*)alloc((size_t)MROWS * 1024 * 2);  // 8 MB
  ushort_t* hbuf   = (ushort_t*)alloc((size_t)MROWS * 1024 * 2);
  float*    x2     = (float*)alloc((size_t)MROWS * 1024 * 4);
  ushort_t* Vtb    = (ushort_t*)alloc((size_t)BB * NH * 64 * SS * 2);  // 8 MB
  ushort_t* ff1    = qkvb;  // reuse qkv(24MB)+ctx(8MB) = 32MB for [4096][4096] bf16
  float*    outp   = (float*)d_out;

  // split-K=2 partials for FFN2 (32 MB); fallback to fused if no room
  const size_t partial1 = (size_t)MROWS * 1024 * 4;  // 16 MB per split
  int S = (ws_size - off >= 2 * partial1 + 256) ? 2 : 1;
  float* pbuf = (S == 2) ? (float*)alloc(2 * partial1) : nullptr;

  // unified prep: weight transposes + bias pack + LN1 (all inputs-independent work)
  prep_kernel<<<dim3(12300 + MROWS), dim3(32, 8), 0, stream>>>(
      Wq, Wk, Wv, Wo, W1, W2, bq, bk, bv, Wt_qkv, Wt_o, Wt_1, Wt_2, bqkv,
      x, ln1w, ln1b, hbuf);

  // fused QKV GEMM: Q/K -> qkvb (Q pre-scaled by Cs); V col-tiles written transposed to Vtb
  gemm256w_kernel<0><<<dim3(32 * 12), 256, 0, stream>>>(
      hbuf, Wt_qkv, bqkv, qkvb, Vtb, MROWS, 3072, 1024, 12);
  // attention: 128 q/block, 512 blocks
  attn_kernel<<<dim3(SS / 128, BB * NH), 256, 0, stream>>>(qkvb, Vtb, ctxb);
  // O-proj + bias + residual(x) -> x2 (fp32), fused
  gemm128_kernel<2><<<dim3(8 * 32), 256, 0, stream>>>(
      ctxb, Wt_o, bo, x, x2, MROWS, 1024, 1024, 8, 1024, 8 * 32);
  // LN2 -> h
  ln_bf16_kernel<<<MROWS, 256, 0, stream>>>(x2, ln2w, ln2b, hbuf);
  // FFN1 + relu -> ff1 (bf16); 128x256 tiles, 512 blocks = exact 2/CU
  gemm256w_kernel<1><<<dim3(32 * 16), 256, 0, stream>>>(
      hbuf, Wt_1, b1, ff1, nullptr, MROWS, D_FF, 1024, 16);
  // FFN2: split-K=2 -> fp32 partials; reduce adds bias b2 + resid x2 -> out
  if (S == 2) {
    gemm128_kernel<3><<<dim3(8 * 32 * 2), 256, 0, stream>>>(
        ff1, Wt_2, nullptr, nullptr, pbuf, MROWS, 1024, 4096, 8, 2048, 8 * 32);
    reduce_kernel<<<2048, 256, 0, stream>>>(pbuf, b2, x2, outp, 2,
        (size_t)MROWS * 1024 / 4, (size_t)MROWS * 1024 / 4);
  } else {
    gemm128_kernel<2><<<dim3(8 * 32), 256, 0, stream>>>(
        ff1, Wt_2, b2, x2, outp, MROWS, 1024, 4096, 8, 4096, 8 * 32);
  }
}